// Round 14
// baseline (3882.085 us; speedup 1.0000x reference)
//
#include <hip/hip_runtime.h>
#include <hip/hip_bf16.h>
#include <math.h>

#define NN 20000
#define NE 640000
#define C 128
#define DE 64
#define ZD 320
#define HD 512
#define G 32
#define LL 3
#define EPSV 1e-5f

typedef __attribute__((ext_vector_type(8))) short bf16x8;
typedef __attribute__((ext_vector_type(4))) float f32x4;
typedef __attribute__((ext_vector_type(16))) float f32x16;

__device__ __forceinline__ ushort f2bf(float f) {
    __hip_bfloat16 h = __float2bfloat16(f);
    return *reinterpret_cast<ushort*>(&h);
}
__device__ __forceinline__ float bf2f(ushort u) {
    return __uint_as_float(((unsigned)u) << 16);
}

// ---------------- graph counting (LDS histogram -> 32 atomics/block) ----------------
__global__ __launch_bounds__(256) void k_gcount(const int* __restrict__ nb, int* __restrict__ gcount) {
    __shared__ int hist[G];
    int t = threadIdx.x;
    if (t < G) hist[t] = 0;
    __syncthreads();
    int i = blockIdx.x * 256 + t;
    if (i < NN) atomicAdd(&hist[nb[i]], 1);
    __syncthreads();
    if (t < G && hist[t] > 0) atomicAdd(&gcount[t], hist[t]);
}

// ---------------- edge sort by dst (counting sort) ----------------
__global__ __launch_bounds__(256) void k_hist(const int* __restrict__ ei, int* __restrict__ deg) {
    int e = blockIdx.x * 256 + threadIdx.x;
    atomicAdd(&deg[ei[NE + e]], 1);
}
__global__ __launch_bounds__(256) void k_scan1(const int* __restrict__ deg, int* __restrict__ cursor,
                                               int* __restrict__ bsum) {
    __shared__ int sh[256];
    int t = threadIdx.x, b = blockIdx.x, i = b * 256 + t;
    int v = (i < NN) ? deg[i] : 0;
    sh[t] = v; __syncthreads();
    for (int off = 1; off < 256; off <<= 1) {
        int u = (t >= off) ? sh[t - off] : 0;
        __syncthreads();
        sh[t] += u;
        __syncthreads();
    }
    if (i < NN) cursor[i] = sh[t] - v;
    if (t == 255) bsum[b] = sh[255];
}
__global__ void k_scan2(const int* __restrict__ bsum, int* __restrict__ boff, int nb) {
    int r = 0;
    for (int b = 0; b < nb; ++b) { boff[b] = r; r += bsum[b]; }
}
__global__ __launch_bounds__(256) void k_scan3(int* __restrict__ cursor, const int* __restrict__ boff) {
    int i = blockIdx.x * 256 + threadIdx.x;
    if (i < NN) cursor[i] += boff[blockIdx.x];
}
__global__ __launch_bounds__(256) void k_scatter(const int* __restrict__ ei, int* __restrict__ cursor,
                                                 int* __restrict__ perm) {
    int e = blockIdx.x * 256 + threadIdx.x;
    int d = ei[NE + e];
    int pos = atomicAdd(&cursor[d], 1);
    perm[pos] = e;
}

// ---------------- permute + cast edge_attr to bf16, sorted order ----------------
__global__ __launch_bounds__(256) void k_permea(const float* __restrict__ ea,
                                                const int* __restrict__ perm,
                                                ushort* __restrict__ out) {
    const int tid = threadIdx.x;
    const int e0 = blockIdx.x * 64;
#pragma unroll
    for (int it = 0; it < 4; ++it) {
        int idx = tid + it * 256;          // 1024 float4-chunks per block
        int e = idx >> 4, f4 = idx & 15;
        int p = perm[e0 + e];
        float4 v = *(const float4*)(ea + (size_t)p * DE + f4 * 4);
        ushort4 o;
        o.x = f2bf(v.x); o.y = f2bf(v.y); o.z = f2bf(v.z); o.w = f2bf(v.w);
        *(ushort4*)(out + (size_t)(e0 + e) * DE + f4 * 4) = o;
    }
}

// ---------------- casts ----------------
__global__ __launch_bounds__(256) void k_cast_x(const float* __restrict__ in, ushort* __restrict__ out) {
    int idx = blockIdx.x * 256 + threadIdx.x;    // n/4 threads
    float4 v = ((const float4*)in)[idx];
    ushort4 o;
    o.x = f2bf(v.x); o.y = f2bf(v.y); o.z = f2bf(v.z); o.w = f2bf(v.w);
    ((ushort4*)out)[idx] = o;
}

// ---------------- MLP weight transposes to k-major (one-time) ----------------
__global__ __launch_bounds__(256) void k_prepw1T(const float* __restrict__ W1, ushort* __restrict__ W1T) {
    int idx = blockIdx.x * 256 + threadIdx.x;      // 3*512*128 = 196608
    int l = idx >> 16, r = idx & 65535;
    int ch = r >> 7, k = r & 127;
    W1T[(size_t)l * 65536 + (((k >> 3) * HD + ch) << 3) + (k & 7)] = f2bf(W1[idx]);
}
__global__ __launch_bounds__(256) void k_prepw2T(const float* __restrict__ W2, ushort* __restrict__ W2T) {
    int idx = blockIdx.x * 256 + threadIdx.x;      // 3*128*512 = 196608
    int l = idx >> 16, r = idx & 65535;
    int ch = r >> 9, k = r & 511;
    W2T[(size_t)l * 65536 + (((k >> 3) * C + ch) << 3) + (k & 7)] = f2bf(W2[idx]);
}

// ---------------- build combined edge weights (bf16), k-major coalesced ----------------
__global__ __launch_bounds__(256) void k_prepw32T(
    const float* __restrict__ Wf, const float* __restrict__ bfv,
    const float* __restrict__ Ws, const float* __restrict__ bsv,
    ushort* __restrict__ Wc, float* __restrict__ bc)
{
    int idx = blockIdx.x * 256 + threadIdx.x;    // 256*320
    int r = idx / 320, k = idx - r * 320;
    int w = r >> 6, half = (r >> 5) & 1, off = r & 31;
    int ch = w * 32 + off;
    const float* W = half ? Ws : Wf;
    Wc[((size_t)(k >> 3) * 256 + r) * 8 + (k & 7)] = f2bf(W[(size_t)ch * ZD + k]);
    if (k == 0) bc[r] = (half ? bsv : bfv)[ch];
}

// ---------------- per-node bases ----------------
// dstbase[n][r] = x_n @ Wc_r[0:128]   + bc[r]  (fp32, into base)
// srcbase[n][r] = x_n @ Wc_r[128:256]          (bf16, into sb16)
__global__ __launch_bounds__(256, 4) void k_base2(
    const ushort* __restrict__ x16, const ushort* __restrict__ Wc,
    const float* __restrict__ bc, float* __restrict__ base, ushort* __restrict__ sb16)
{
    __shared__ ushort xs[32][136];
    const int tid = threadIdx.x;
    const int n0 = blockIdx.x * 32;          // 625 blocks x 32 nodes = 20000 exact
#pragma unroll
    for (int it = 0; it < 2; ++it) {
        int idx = tid + it * 256;            // 512 chunks (32 nodes x 16)
        int n = idx >> 4, c = (idx & 15) * 8;
        *(uint4*)(&xs[n][c]) = *(const uint4*)(x16 + (size_t)(n0 + n) * C + c);
    }
    __syncthreads();
    const int w = tid >> 6, l = tid & 63;
    const int col = l & 31, hi = l >> 5;
    f32x16 d0, d1, s0, s1;
#pragma unroll
    for (int i = 0; i < 16; ++i) { d0[i] = 0.f; d1[i] = 0.f; s0[i] = 0.f; s1[i] = 0.f; }
    const ushort* wd0 = Wc + ((size_t)hi * 256 + w * 64 + col) * 8;         // dst chunks hi..
    const ushort* wd1 = wd0 + 32 * 8;
    const ushort* wsr0 = Wc + ((size_t)(16 + hi) * 256 + w * 64 + col) * 8; // src chunks 16+hi..
    const ushort* wsr1 = wsr0 + 32 * 8;
#pragma unroll
    for (int kk = 0; kk < 8; ++kk) {         // K = 128 per part
        const int k0 = kk * 16 + hi * 8;
        const size_t off = (size_t)kk * 2 * 256 * 8;
        bf16x8 a = *(const bf16x8*)(&xs[col][k0]);
        d0 = __builtin_amdgcn_mfma_f32_32x32x16_bf16(a, *(const bf16x8*)(wd0 + off), d0, 0, 0, 0);
        d1 = __builtin_amdgcn_mfma_f32_32x32x16_bf16(a, *(const bf16x8*)(wd1 + off), d1, 0, 0, 0);
        s0 = __builtin_amdgcn_mfma_f32_32x32x16_bf16(a, *(const bf16x8*)(wsr0 + off), s0, 0, 0, 0);
        s1 = __builtin_amdgcn_mfma_f32_32x32x16_bf16(a, *(const bf16x8*)(wsr1 + off), s1, 0, 0, 0);
    }
    const int r0 = w * 64 + col;
    const float bg = bc[r0], bs = bc[r0 + 32];
#pragma unroll
    for (int q = 0; q < 16; ++q) {
        int nl = (q & 3) + 8 * (q >> 2) + 4 * hi;
        float* brow = base + (size_t)(n0 + nl) * 256;
        brow[r0] = d0[q] + bg;
        brow[r0 + 32] = d1[q] + bs;
        ushort* srow = sb16 + (size_t)(n0 + nl) * 256;
        srow[r0] = f2bf(s0[q]);
        srow[r0 + 32] = f2bf(s1[q]);
    }
}

// ---------------- CGConv edge kernel: 32 edges/block, K=64 (ea only) ----------------
// Both x contributions hoisted to per-node bases; GEMM is ea @ Wc[256:320] only.
template<bool SEA>
__global__ __launch_bounds__(256, 8) void k_edge32s(
    const int* __restrict__ ei, const int* __restrict__ perm,
    const float* __restrict__ ea, const ushort* __restrict__ ea16p,
    const ushort* __restrict__ Wc, const float* __restrict__ base,
    const ushort* __restrict__ sb16, float* __restrict__ xnew)
{
    __shared__ ushort zt[32][72];            // 64 + 8 pad
    __shared__ __align__(16) int s_dst[32];
    __shared__ __align__(16) int s_src[32];
    __shared__ int s_perm[32];
    const int tid = threadIdx.x;
    const int bid = blockIdx.x;
    const int swz = (bid & 7) * (NE / 32 / 8) + (bid >> 3);   // bijective: 20000 % 8 == 0
    const int e0 = swz * 32;
    if (tid < 32) {
        int p = perm[e0 + tid];
        s_perm[tid] = p;
        s_src[tid] = ei[p];
        s_dst[tid] = ei[NE + p];
    }
    __syncthreads();

    // gather ea: 32 edges x 8 chunks = 256, 1 per thread
    {
        int e = tid >> 3, r = tid & 7;
        if (SEA) {
            *(uint4*)(&zt[e][r * 8]) = *(const uint4*)(ea16p + (size_t)(e0 + e) * DE + r * 8);
        } else {
            const float* s = ea + (size_t)s_perm[e] * DE + r * 8;
            float4 u = *(const float4*)s;
            float4 v = *(const float4*)(s + 4);
            ushort o[8];
            o[0] = f2bf(u.x); o[1] = f2bf(u.y); o[2] = f2bf(u.z); o[3] = f2bf(u.w);
            o[4] = f2bf(v.x); o[5] = f2bf(v.y); o[6] = f2bf(v.z); o[7] = f2bf(v.w);
            *(uint4*)(&zt[e][r * 8]) = *(uint4*)o;
        }
    }
    __syncthreads();

    const int w = tid >> 6, l = tid & 63;
    const int col = l & 31;
    const int hi = l >> 5;
    f32x16 acc0, acc1;
#pragma unroll
    for (int i = 0; i < 16; ++i) { acc0[i] = 0.f; acc1[i] = 0.f; }

    // ea section: K-global 256..320 -> chunks 32..39; chunk = 32 + kk*2 + hi
    const ushort* wb0 = Wc + ((size_t)(32 + hi) * 256 + w * 64 + col) * 8;
    const ushort* wb1 = wb0 + 32 * 8;
#pragma unroll
    for (int kk = 0; kk < 4; ++kk) {         // K = 64
        const int k0 = kk * 16 + hi * 8;
        const size_t off = (size_t)kk * 2 * 256 * 8;
        bf16x8 a = *(const bf16x8*)(&zt[col][k0]);
        acc0 = __builtin_amdgcn_mfma_f32_32x32x16_bf16(a, *(const bf16x8*)(wb0 + off), acc0, 0, 0, 0);
        acc1 = __builtin_amdgcn_mfma_f32_32x32x16_bf16(a, *(const bf16x8*)(wb1 + off), acc1, 0, 0, 0);
    }

    // epilogue: lane owns 16 edges x 1 channel; dstbase run-merged, srcbase per edge
    const float L2E = 1.44269504f, LN2 = 0.69314718f;
    const int ch = w * 32 + col;
    const int r0 = w * 64 + col;
    float run = 0.f;
    int prevd = s_dst[4 * hi];
    float bg = base[(size_t)prevd * 256 + r0];
    float bsv = base[(size_t)prevd * 256 + r0 + 32];
#pragma unroll
    for (int grp = 0; grp < 4; ++grp) {
        const int4 d4 = *(const int4*)(&s_dst[grp * 8 + 4 * hi]);
        const int4 sc4 = *(const int4*)(&s_src[grp * 8 + 4 * hi]);
#pragma unroll
        for (int j = 0; j < 4; ++j) {
            const int q = grp * 4 + j;
            const int d = (j == 0) ? d4.x : (j == 1) ? d4.y : (j == 2) ? d4.z : d4.w;
            const int sc = (j == 0) ? sc4.x : (j == 1) ? sc4.y : (j == 2) ? sc4.z : sc4.w;
            if (d != prevd) {
                unsafeAtomicAdd(xnew + (size_t)prevd * C + ch, run);
                run = 0.f;
                prevd = d;
                bg = base[(size_t)d * 256 + r0];
                bsv = base[(size_t)d * 256 + r0 + 32];
            }
            const ushort* srow = sb16 + (size_t)sc * 256;
            float g = acc0[q] + bg + bf2f(srow[r0]);
            float s = acc1[q] + bsv + bf2f(srow[r0 + 32]);
            float gate = __builtin_amdgcn_rcpf(1.0f + __builtin_amdgcn_exp2f(-L2E * g));
            float sp = fmaf(LN2,
                            __builtin_amdgcn_logf(1.0f + __builtin_amdgcn_exp2f(-L2E * fabsf(s))),
                            fmaxf(s, 0.0f));
            run = fmaf(gate, sp, run);
        }
    }
    unsafeAtomicAdd(xnew + (size_t)prevd * C + ch, run);
}

// ---------------- MLP GEMM1 (MFMA): fp32 in, h16 = bf16(x @ W1^T + b1), col stats ----------------
__global__ __launch_bounds__(256) void k_mlp1_mfma(
    const float* __restrict__ x, const ushort* __restrict__ W1T,
    const float* __restrict__ b1, ushort* __restrict__ h16,
    float* __restrict__ colsum, float* __restrict__ colsq)
{
    __shared__ ushort xs[64][136];
    const int tid = threadIdx.x;
    const int n0 = blockIdx.x * 64;
    const int ch0 = blockIdx.y * 128;
#pragma unroll
    for (int it = 0; it < 4; ++it) {
        int idx = tid + it * 256;       // 1024 chunks
        int e = idx >> 4, c = (idx & 15) * 8;
        int rr = n0 + e; if (rr >= NN) rr = NN - 1;
        const float* s = x + (size_t)rr * C + c;
        float4 u = *(const float4*)s;
        float4 v = *(const float4*)(s + 4);
        ushort o[8];
        o[0] = f2bf(u.x); o[1] = f2bf(u.y); o[2] = f2bf(u.z); o[3] = f2bf(u.w);
        o[4] = f2bf(v.x); o[5] = f2bf(v.y); o[6] = f2bf(v.z); o[7] = f2bf(v.w);
        *(uint4*)(&xs[e][c]) = *(uint4*)o;
    }
    __syncthreads();
    const int w = tid >> 6, l = tid & 63, lr = l & 15, lq = l >> 4, kp = lq * 8;
    const int cb = ch0 + w * 32;
    f32x4 acc[4][2];
#pragma unroll
    for (int rt = 0; rt < 4; ++rt) { acc[rt][0] = (f32x4){0,0,0,0}; acc[rt][1] = (f32x4){0,0,0,0}; }
    for (int kk = 0; kk < 4; ++kk) {
        int k0 = kk * 32 + kp;
        bf16x8 a[4], b[2];
#pragma unroll
        for (int rt = 0; rt < 4; ++rt) a[rt] = *(const bf16x8*)(&xs[rt * 16 + lr][k0]);
#pragma unroll
        for (int j = 0; j < 2; ++j)
            b[j] = *(const bf16x8*)(W1T + (((size_t)(kk * 4 + lq) * HD + cb + j * 16 + lr) << 3));
#pragma unroll
        for (int rt = 0; rt < 4; ++rt)
#pragma unroll
            for (int j = 0; j < 2; ++j)
                acc[rt][j] = __builtin_amdgcn_mfma_f32_16x16x32_bf16(a[rt], b[j], acc[rt][j], 0, 0, 0);
    }
    const int ro = lq * 4;
    float ps[2] = {0.f, 0.f}, pq[2] = {0.f, 0.f};
#pragma unroll
    for (int j = 0; j < 2; ++j) {
        const int ch = cb + j * 16 + lr;
        const float bv = b1[ch];
#pragma unroll
        for (int rt = 0; rt < 4; ++rt) {
#pragma unroll
            for (int q = 0; q < 4; ++q) {
                int row = n0 + rt * 16 + ro + q;
                float hv = acc[rt][j][q] + bv;
                if (row < NN) {
                    h16[(size_t)row * HD + ch] = f2bf(hv);
                    ps[j] += hv; pq[j] += hv * hv;
                }
            }
        }
    }
#pragma unroll
    for (int j = 0; j < 2; ++j) {
        ps[j] += __shfl_xor(ps[j], 16); ps[j] += __shfl_xor(ps[j], 32);
        pq[j] += __shfl_xor(pq[j], 16); pq[j] += __shfl_xor(pq[j], 32);
    }
    if (l < 16) {
#pragma unroll
        for (int j = 0; j < 2; ++j) {
            unsafeAtomicAdd(colsum + cb + j * 16 + lr, ps[j]);
            unsafeAtomicAdd(colsq + cb + j * 16 + lr, pq[j]);
        }
    }
}

// finalizes BN affine and re-zeros colsum/colsq for the next layer
__global__ void k_bnstats(float* __restrict__ colsum, float* __restrict__ colsq,
                          const float* __restrict__ g1, const float* __restrict__ be1,
                          float* __restrict__ bn_a, float* __restrict__ bn_b) {
    int c = threadIdx.x;   // 512
    float m = colsum[c] * (1.0f / NN);
    float v = colsq[c] * (1.0f / NN) - m * m;
    float istd = rsqrtf(fmaxf(v, 0.f) + EPSV);
    float a = g1[c] * istd;
    bn_a[c] = a;
    bn_b[c] = fmaf(-m, a, be1[c]);
    colsum[c] = 0.f;
    colsq[c] = 0.f;
}

// ---------------- MLP GEMM2 (MFMA): x = xres + relu(a*h+b) @ W2^T + b2 ----------------
__global__ __launch_bounds__(256) void k_mlp2_mfma(
    const ushort* __restrict__ h16, const float* __restrict__ bn_a, const float* __restrict__ bn_b,
    const ushort* __restrict__ W2T, const float* __restrict__ b2,
    const float* __restrict__ xres, float* __restrict__ xout)
{
    __shared__ ushort hs[64][136];
    const int tid = threadIdx.x;
    const int n0 = blockIdx.x * 64;
    const int w = tid >> 6, l = tid & 63, lr = l & 15, lq = l >> 4, kp = lq * 8;
    f32x4 acc[4][2];
#pragma unroll
    for (int rt = 0; rt < 4; ++rt) { acc[rt][0] = (f32x4){0,0,0,0}; acc[rt][1] = (f32x4){0,0,0,0}; }

    for (int kc = 0; kc < 4; ++kc) {
#pragma unroll
        for (int it = 0; it < 4; ++it) {
            int idx = tid + it * 256;
            int e = idx >> 4, c = (idx & 15) * 8;
            int rr = n0 + e; if (rr >= NN) rr = NN - 1;
            int k = kc * 128 + c;
            bf16x8 hv = *(const bf16x8*)(h16 + (size_t)rr * HD + k);
            ushort o[8];
#pragma unroll
            for (int m = 0; m < 8; ++m) {
                float f = bf2f((ushort)hv[m]);
                f = fmaf(bn_a[k + m], f, bn_b[k + m]);
                o[m] = f2bf(fmaxf(f, 0.f));
            }
            *(uint4*)(&hs[e][c]) = *(uint4*)o;
        }
        __syncthreads();
        for (int kk = 0; kk < 4; ++kk) {
            int k0 = kk * 32 + kp;
            bf16x8 a[4], b[2];
#pragma unroll
            for (int rt = 0; rt < 4; ++rt) a[rt] = *(const bf16x8*)(&hs[rt * 16 + lr][k0]);
#pragma unroll
            for (int j = 0; j < 2; ++j)
                b[j] = *(const bf16x8*)(W2T + (((size_t)(kc * 16 + kk * 4 + lq) * C + w * 32 + j * 16 + lr) << 3));
#pragma unroll
            for (int rt = 0; rt < 4; ++rt)
#pragma unroll
                for (int j = 0; j < 2; ++j)
                    acc[rt][j] = __builtin_amdgcn_mfma_f32_16x16x32_bf16(a[rt], b[j], acc[rt][j], 0, 0, 0);
        }
        __syncthreads();
    }
    const int ro = lq * 4;
#pragma unroll
    for (int j = 0; j < 2; ++j) {
        const int ch = w * 32 + j * 16 + lr;
        const float bv = b2[ch];
#pragma unroll
        for (int rt = 0; rt < 4; ++rt) {
#pragma unroll
            for (int q = 0; q < 4; ++q) {
                int row = n0 + rt * 16 + ro + q;
                if (row < NN)
                    xout[(size_t)row * C + ch] = xres[(size_t)row * C + ch] + acc[rt][j][q] + bv;
            }
        }
    }
}

// ---------------- graph LayerNorm stats (block-level reduce, run-merged atomics) ----------------
__global__ __launch_bounds__(256) void k_lnstats(
    const float* __restrict__ x2, const int* __restrict__ nb_arr,
    float* __restrict__ gsum, float* __restrict__ gsq)
{
    __shared__ float sh_s[64], sh_q[64];
    __shared__ int sh_g[64];
    const int tid = threadIdx.x;
    const int nl = tid >> 2;                 // node-local 0..63
    const int node = blockIdx.x * 64 + nl;
    const int sub = tid & 3;
    const int nvalid = min(64, NN - blockIdx.x * 64);
    if (node < NN) {
        const float4* row = (const float4*)(x2 + (size_t)node * C);
        float s = 0.f, q = 0.f;
#pragma unroll
        for (int t = 0; t < 8; ++t) {
            float4 v = row[sub + 4 * t];
            s += v.x + v.y + v.z + v.w;
            q += v.x * v.x + v.y * v.y + v.z * v.z + v.w * v.w;
        }
        s += __shfl_xor(s, 1); q += __shfl_xor(q, 1);
        s += __shfl_xor(s, 2); q += __shfl_xor(q, 2);
        if (sub == 0) {
            sh_s[nl] = s; sh_q[nl] = q; sh_g[nl] = nb_arr[node];
        }
    }
    __syncthreads();
    if (tid == 0) {
        int pg = sh_g[0];
        float rs = 0.f, rq = 0.f;
        for (int i = 0; i < nvalid; ++i) {
            int g = sh_g[i];
            if (g != pg) {
                unsafeAtomicAdd(&gsum[pg], rs);
                unsafeAtomicAdd(&gsq[pg], rq);
                rs = 0.f; rq = 0.f; pg = g;
            }
            rs += sh_s[i]; rq += sh_q[i];
        }
        unsafeAtomicAdd(&gsum[pg], rs);
        unsafeAtomicAdd(&gsq[pg], rq);
    }
}

// finalizes LN mean/istd and re-zeros gsum/gsq for the next layer
__global__ void k_lnfin(float* __restrict__ gsum, float* __restrict__ gsq,
                        const int* __restrict__ gcount,
                        float* __restrict__ gmean, float* __restrict__ gistd) {
    int g = threadIdx.x;
    float cnt = fmaxf((float)gcount[g], 1.0f) * (float)C;
    float m = gsum[g] / cnt;
    float v = gsq[g] / cnt - m * m;
    gmean[g] = m;
    gistd[g] = rsqrtf(fmaxf(v, 0.f) + EPSV);
    gsum[g] = 0.f;
    gsq[g] = 0.f;
}

// fused: fp32 out (+ optional bf16 copy for next edge layer + fp32 residual copy)
__global__ __launch_bounds__(256) void k_lnapply(
    const float* __restrict__ x2, const int* __restrict__ nb_arr,
    const float* __restrict__ gmean, const float* __restrict__ gistd,
    const float* __restrict__ lnw, const float* __restrict__ lnb,
    float* __restrict__ out, ushort* __restrict__ bfout, float* __restrict__ xbout, int aux)
{
    int idx = blockIdx.x * 256 + threadIdx.x;   // NC/4 threads
    int elem = idx * 4;
    int n = elem >> 7, c = elem & 127;
    int g = nb_arr[n];
    float m = gmean[g], is = gistd[g];
    float4 v = *(const float4*)(x2 + elem);
    float4 wv = *(const float4*)(lnw + c);
    float4 bv = *(const float4*)(lnb + c);
    float4 r;
    r.x = (v.x - m) * is * wv.x + bv.x;
    r.y = (v.y - m) * is * wv.y + bv.y;
    r.z = (v.z - m) * is * wv.z + bv.z;
    r.w = (v.w - m) * is * wv.w + bv.w;
    *(float4*)(out + elem) = r;
    if (aux) {
        ushort4 o;
        o.x = f2bf(r.x); o.y = f2bf(r.y); o.z = f2bf(r.z); o.w = f2bf(r.w);
        *(ushort4*)(bfout + elem) = o;
        *(float4*)(xbout + elem) = r;
    }
}

// ---------------- launcher ----------------
extern "C" void kernel_launch(void* const* d_in, const int* in_sizes, int n_in,
                              void* d_out, int out_size, void* d_ws, size_t ws_size,
                              hipStream_t stream) {
    const float* x_in = (const float*)d_in[0];
    const int* node_batch = (const int*)d_in[1];
    const int* ei = (const int*)d_in[2];
    const float* ea = (const float*)d_in[3];
    const float* Wf = (const float*)d_in[4];
    const float* bfv = (const float*)d_in[5];
    const float* Ws = (const float*)d_in[6];
    const float* bsv = (const float*)d_in[7];
    const float* W1 = (const float*)d_in[8];
    const float* b1 = (const float*)d_in[9];
    const float* g1 = (const float*)d_in[10];
    const float* be1 = (const float*)d_in[11];
    const float* W2 = (const float*)d_in[12];
    const float* b2 = (const float*)d_in[13];
    const float* lnw = (const float*)d_in[14];
    const float* lnb = (const float*)d_in[15];
    float* out = (float*)d_out;

    const size_t NC = (size_t)NN * C;       // 2,560,000
    const size_t NH = (size_t)NN * HD;      // 10,240,000
    float* p = (float*)d_ws;
    float* xa = p; p += NC;
    float* xb = p; p += NC;
    ushort* h16 = (ushort*)p; p += NH / 2;  // base[N][256] fp32 aliases this (exactly NH/2 floats)
    float* base = (float*)h16;
    ushort* bfx = (ushort*)p; p += NC / 2;
    ushort* Wce = (ushort*)p; p += 40960;          // 81920 ushorts
    ushort* W116 = (ushort*)p; p += 98304;         // 3*65536 ushorts (k-major)
    ushort* W216 = (ushort*)p; p += 98304;
    float* bc = p; p += 256;
    float* bn_a = p; p += 512;
    float* bn_b = p; p += 512;
    float* colsum = p; p += 512;
    float* colsq = p; p += 512;                    // contiguous with colsum
    float* gsum = p; p += 32;
    float* gsq = p; p += 32;                       // contiguous with gsum
    float* gmean = p; p += 32;
    float* gistd = p; p += 32;
    int* gcount = (int*)p; p += 32;
    int* deg = (int*)p; p += NN;
    int* cursor = (int*)p; p += NN;
    int* bsum = (int*)p; p += 128;
    int* boff = (int*)p; p += 128;
    int* perm = (int*)p; p += NE;
    ushort* sb16 = (ushort*)p; p += (size_t)NN * 256 / 2;   // srcbase bf16 (mandatory)
    ushort* ea16p = (ushort*)p; p += (size_t)NE * DE / 2;   // optional 82 MB

    const bool sea = ws_size >= (size_t)((char*)p - (char*)d_ws);
    const int NB_SCAN = (NN + 255) / 256;          // 79

    // ---- one-time per call: sort edges by dst, graph counts, weight preps ----
    hipMemsetAsync(deg, 0, NN * 4, stream);
    k_hist<<<NE / 256, 256, 0, stream>>>(ei, deg);
    k_scan1<<<NB_SCAN, 256, 0, stream>>>(deg, cursor, bsum);
    k_scan2<<<1, 1, 0, stream>>>(bsum, boff, NB_SCAN);
    k_scan3<<<NB_SCAN, 256, 0, stream>>>(cursor, boff);
    k_scatter<<<NE / 256, 256, 0, stream>>>(ei, cursor, perm);
    if (sea) k_permea<<<NE / 64, 256, 0, stream>>>(ea, perm, ea16p);

    hipMemsetAsync(gcount, 0, G * 4, stream);
    k_gcount<<<(NN + 255) / 256, 256, 0, stream>>>(node_batch, gcount);

    k_prepw1T<<<768, 256, 0, stream>>>(W1, W116);
    k_prepw2T<<<768, 256, 0, stream>>>(W2, W216);

    // stats accumulators zeroed once; producers re-zero them each layer
    hipMemsetAsync(colsum, 0, 1024 * 4, stream);
    hipMemsetAsync(gsum, 0, 64 * 4, stream);

    hipMemcpyAsync(xa, x_in, NC * 4, hipMemcpyDeviceToDevice, stream);
    hipMemcpyAsync(xb, x_in, NC * 4, hipMemcpyDeviceToDevice, stream);
    k_cast_x<<<NC / 1024, 256, 0, stream>>>(x_in, bfx);

    for (int l = 0; l < LL; ++l) {
        k_prepw32T<<<320, 256, 0, stream>>>(
            Wf + (size_t)l * C * ZD, bfv + (size_t)l * C,
            Ws + (size_t)l * C * ZD, bsv + (size_t)l * C, Wce, bc);
        k_base2<<<NN / 32, 256, 0, stream>>>(bfx, Wce, bc, base, sb16);
        // xb already holds x (residual); edge accumulates messages into it
        if (sea)
            k_edge32s<true><<<NE / 32, 256, 0, stream>>>(ei, perm, ea, ea16p, Wce, base, sb16, xb);
        else
            k_edge32s<false><<<NE / 32, 256, 0, stream>>>(ei, perm, ea, ea16p, Wce, base, sb16, xb);

        k_mlp1_mfma<<<dim3(313, 4), 256, 0, stream>>>(xb,
            W116 + (size_t)l * 65536, b1 + (size_t)l * HD, h16, colsum, colsq);
        k_bnstats<<<1, HD, 0, stream>>>(colsum, colsq,
            g1 + (size_t)l * HD, be1 + (size_t)l * HD, bn_a, bn_b);

        k_mlp2_mfma<<<313, 256, 0, stream>>>(h16, bn_a, bn_b,
            W216 + (size_t)l * 65536, b2 + (size_t)l * C, xb, xa);

        k_lnstats<<<(NN + 63) / 64, 256, 0, stream>>>(xa, node_batch, gsum, gsq);
        k_lnfin<<<1, G, 0, stream>>>(gsum, gsq, gcount, gmean, gistd);
        float* dstp = (l == LL - 1) ? out : xa;
        k_lnapply<<<NC / 1024, 256, 0, stream>>>(xa, node_batch, gmean, gistd,
            lnw + (size_t)l * C, lnb + (size_t)l * C, dstp, bfx, xb, (l != LL - 1) ? 1 : 0);
    }
}

// Round 15
// 3397.153 us; speedup vs baseline: 1.1427x; 1.1427x over previous
//
#include <hip/hip_runtime.h>
#include <hip/hip_bf16.h>
#include <math.h>

#define NN 20000
#define NE 640000
#define C 128
#define DE 64
#define ZD 320
#define HD 512
#define G 32
#define LL 3
#define EPSV 1e-5f

typedef __attribute__((ext_vector_type(8))) short bf16x8;
typedef __attribute__((ext_vector_type(4))) float f32x4;
typedef __attribute__((ext_vector_type(16))) float f32x16;

__device__ __forceinline__ ushort f2bf(float f) {
    __hip_bfloat16 h = __float2bfloat16(f);
    return *reinterpret_cast<ushort*>(&h);
}
__device__ __forceinline__ float bf2f(ushort u) {
    return __uint_as_float(((unsigned)u) << 16);
}

// ---------------- graph counting (LDS histogram -> 32 atomics/block) ----------------
__global__ __launch_bounds__(256) void k_gcount(const int* __restrict__ nb, int* __restrict__ gcount) {
    __shared__ int hist[G];
    int t = threadIdx.x;
    if (t < G) hist[t] = 0;
    __syncthreads();
    int i = blockIdx.x * 256 + t;
    if (i < NN) atomicAdd(&hist[nb[i]], 1);
    __syncthreads();
    if (t < G && hist[t] > 0) atomicAdd(&gcount[t], hist[t]);
}

// ---------------- edge sort by dst (counting sort) ----------------
__global__ __launch_bounds__(256) void k_hist(const int* __restrict__ ei, int* __restrict__ deg) {
    int e = blockIdx.x * 256 + threadIdx.x;
    atomicAdd(&deg[ei[NE + e]], 1);
}
__global__ __launch_bounds__(256) void k_scan1(const int* __restrict__ deg, int* __restrict__ cursor,
                                               int* __restrict__ bsum) {
    __shared__ int sh[256];
    int t = threadIdx.x, b = blockIdx.x, i = b * 256 + t;
    int v = (i < NN) ? deg[i] : 0;
    sh[t] = v; __syncthreads();
    for (int off = 1; off < 256; off <<= 1) {
        int u = (t >= off) ? sh[t - off] : 0;
        __syncthreads();
        sh[t] += u;
        __syncthreads();
    }
    if (i < NN) cursor[i] = sh[t] - v;
    if (t == 255) bsum[b] = sh[255];
}
__global__ void k_scan2(const int* __restrict__ bsum, int* __restrict__ boff, int nb) {
    int r = 0;
    for (int b = 0; b < nb; ++b) { boff[b] = r; r += bsum[b]; }
}
__global__ __launch_bounds__(256) void k_scan3(int* __restrict__ cursor, const int* __restrict__ boff) {
    int i = blockIdx.x * 256 + threadIdx.x;
    if (i < NN) cursor[i] += boff[blockIdx.x];
}
__global__ __launch_bounds__(256) void k_scatter(const int* __restrict__ ei, int* __restrict__ cursor,
                                                 int* __restrict__ perm) {
    int e = blockIdx.x * 256 + threadIdx.x;
    int d = ei[NE + e];
    int pos = atomicAdd(&cursor[d], 1);
    perm[pos] = e;
}

// ---------------- permute + cast edge_attr to bf16, sorted order ----------------
__global__ __launch_bounds__(256) void k_permea(const float* __restrict__ ea,
                                                const int* __restrict__ perm,
                                                ushort* __restrict__ out) {
    const int tid = threadIdx.x;
    const int e0 = blockIdx.x * 64;
#pragma unroll
    for (int it = 0; it < 4; ++it) {
        int idx = tid + it * 256;          // 1024 float4-chunks per block
        int e = idx >> 4, f4 = idx & 15;
        int p = perm[e0 + e];
        float4 v = *(const float4*)(ea + (size_t)p * DE + f4 * 4);
        ushort4 o;
        o.x = f2bf(v.x); o.y = f2bf(v.y); o.z = f2bf(v.z); o.w = f2bf(v.w);
        *(ushort4*)(out + (size_t)(e0 + e) * DE + f4 * 4) = o;
    }
}

// ---------------- casts ----------------
__global__ __launch_bounds__(256) void k_cast_x(const float* __restrict__ in, ushort* __restrict__ out) {
    int idx = blockIdx.x * 256 + threadIdx.x;    // n/4 threads
    float4 v = ((const float4*)in)[idx];
    ushort4 o;
    o.x = f2bf(v.x); o.y = f2bf(v.y); o.z = f2bf(v.z); o.w = f2bf(v.w);
    ((ushort4*)out)[idx] = o;
}

// ---------------- MLP weight transposes to k-major (one-time) ----------------
__global__ __launch_bounds__(256) void k_prepw1T(const float* __restrict__ W1, ushort* __restrict__ W1T) {
    int idx = blockIdx.x * 256 + threadIdx.x;      // 3*512*128 = 196608
    int l = idx >> 16, r = idx & 65535;
    int ch = r >> 7, k = r & 127;
    W1T[(size_t)l * 65536 + (((k >> 3) * HD + ch) << 3) + (k & 7)] = f2bf(W1[idx]);
}
__global__ __launch_bounds__(256) void k_prepw2T(const float* __restrict__ W2, ushort* __restrict__ W2T) {
    int idx = blockIdx.x * 256 + threadIdx.x;      // 3*128*512 = 196608
    int l = idx >> 16, r = idx & 65535;
    int ch = r >> 9, k = r & 511;
    W2T[(size_t)l * 65536 + (((k >> 3) * C + ch) << 3) + (k & 7)] = f2bf(W2[idx]);
}

// ---------------- build combined edge weights (bf16), k-major coalesced ----------------
__global__ __launch_bounds__(256) void k_prepw32T(
    const float* __restrict__ Wf, const float* __restrict__ bfv,
    const float* __restrict__ Ws, const float* __restrict__ bsv,
    ushort* __restrict__ Wc, float* __restrict__ bc)
{
    int idx = blockIdx.x * 256 + threadIdx.x;    // 256*320
    int r = idx / 320, k = idx - r * 320;
    int w = r >> 6, half = (r >> 5) & 1, off = r & 31;
    int ch = w * 32 + off;
    const float* W = half ? Ws : Wf;
    Wc[((size_t)(k >> 3) * 256 + r) * 8 + (k & 7)] = f2bf(W[(size_t)ch * ZD + k]);
    if (k == 0) bc[r] = (half ? bsv : bfv)[ch];
}

// ---------------- per-node base: base[n][r] = x_n @ Wc_r[0:128]^T + bc[r] ----------------
__global__ __launch_bounds__(256, 8) void k_base(
    const ushort* __restrict__ x16, const ushort* __restrict__ Wc,
    const float* __restrict__ bc, float* __restrict__ base)
{
    __shared__ ushort xs[32][136];
    const int tid = threadIdx.x;
    const int n0 = blockIdx.x * 32;          // 625 blocks x 32 nodes = 20000 exact
#pragma unroll
    for (int it = 0; it < 2; ++it) {
        int idx = tid + it * 256;            // 512 chunks (32 nodes x 16)
        int n = idx >> 4, c = (idx & 15) * 8;
        *(uint4*)(&xs[n][c]) = *(const uint4*)(x16 + (size_t)(n0 + n) * C + c);
    }
    __syncthreads();
    const int w = tid >> 6, l = tid & 63;
    const int col = l & 31, hi = l >> 5;
    f32x16 acc0, acc1;
#pragma unroll
    for (int i = 0; i < 16; ++i) { acc0[i] = 0.f; acc1[i] = 0.f; }
    const ushort* wb0 = Wc + ((size_t)hi * 256 + w * 64 + col) * 8;
    const ushort* wb1 = wb0 + 32 * 8;
#pragma unroll
    for (int kk = 0; kk < 8; ++kk) {         // K = 128 (x section, chunks 0..15)
        const int k0 = kk * 16 + hi * 8;
        bf16x8 a = *(const bf16x8*)(&xs[col][k0]);
        bf16x8 b0 = *(const bf16x8*)(wb0 + (size_t)kk * 2 * 256 * 8);
        bf16x8 b1 = *(const bf16x8*)(wb1 + (size_t)kk * 2 * 256 * 8);
        acc0 = __builtin_amdgcn_mfma_f32_32x32x16_bf16(a, b0, acc0, 0, 0, 0);
        acc1 = __builtin_amdgcn_mfma_f32_32x32x16_bf16(a, b1, acc1, 0, 0, 0);
    }
    const int r0 = w * 64 + col;
    const float bg = bc[r0], bs = bc[r0 + 32];
#pragma unroll
    for (int q = 0; q < 16; ++q) {
        int nl = (q & 3) + 8 * (q >> 2) + 4 * hi;
        float* brow = base + (size_t)(n0 + nl) * 256;
        brow[r0] = acc0[q] + bg;
        brow[r0 + 32] = acc1[q] + bs;
    }
}

// ---------------- CGConv edge kernel: 64 edges/block, K=192, shared B-frags ----------------
// Epilogue: exp2/log2/rcp forms (no IEEE div, no libm const-muls), int4 dst loads.
// launch_bounds(256,6): LDS 26.4 KB -> exactly 6 blocks/CU (158 KB), VGPR 48 < 85 cap.
template<bool SEA>
__global__ __launch_bounds__(256, 6) void k_edge64(
    const ushort* __restrict__ x16, const int* __restrict__ ei,
    const int* __restrict__ perm, const float* __restrict__ ea,
    const ushort* __restrict__ ea16p, const ushort* __restrict__ Wc,
    const float* __restrict__ base, float* __restrict__ xnew)
{
    __shared__ ushort zt[64][200];           // 192 + 8 pad
    __shared__ __align__(16) int s_dst[64];
    __shared__ int s_src[64], s_perm[64];
    const int tid = threadIdx.x;
    const int bid = blockIdx.x;
    const int swz = (bid & 7) * (NE / 64 / 8) + (bid >> 3);   // bijective: 10000 % 8 == 0
    const int e0 = swz * 64;
    if (tid < 64) {
        int p = perm[e0 + tid];
        s_perm[tid] = p;
        s_src[tid] = ei[p];
        s_dst[tid] = ei[NE + p];
    }
    __syncthreads();

    // gather x_src: 64 edges x 16 chunks = 1024, shift/mask only
#pragma unroll
    for (int it = 0; it < 4; ++it) {
        int idx = tid + it * 256;
        int e = idx >> 4, r = idx & 15;
        *(uint4*)(&zt[e][r * 8]) = *(const uint4*)(x16 + (size_t)s_src[e] * C + r * 8);
    }
    // gather ea: 64 edges x 8 chunks = 512
    if (SEA) {
#pragma unroll
        for (int it = 0; it < 2; ++it) {
            int idx = tid + it * 256;
            int e = idx >> 3, r = idx & 7;
            *(uint4*)(&zt[e][128 + r * 8]) =
                *(const uint4*)(ea16p + (size_t)(e0 + e) * DE + r * 8);
        }
    } else {
#pragma unroll
        for (int it = 0; it < 2; ++it) {
            int idx = tid + it * 256;
            int e = idx >> 3, r = idx & 7;
            const float* s = ea + (size_t)s_perm[e] * DE + r * 8;
            float4 u = *(const float4*)s;
            float4 v = *(const float4*)(s + 4);
            ushort o[8];
            o[0] = f2bf(u.x); o[1] = f2bf(u.y); o[2] = f2bf(u.z); o[3] = f2bf(u.w);
            o[4] = f2bf(v.x); o[5] = f2bf(v.y); o[6] = f2bf(v.z); o[7] = f2bf(v.w);
            *(uint4*)(&zt[e][128 + r * 8]) = *(uint4*)o;
        }
    }
    __syncthreads();

    const int w = tid >> 6, l = tid & 63;
    const int col = l & 31;
    const int hi = l >> 5;
    f32x16 acc0[2], acc1[2];                 // [edge-tile][gate/softplus]
#pragma unroll
    for (int i = 0; i < 16; ++i) {
        acc0[0][i] = 0.f; acc1[0][i] = 0.f; acc0[1][i] = 0.f; acc1[1][i] = 0.f;
    }

    // K-global = 128 + kk*16 + hi*8 -> chunk = 16 + kk*2 + hi
    const ushort* wb0 = Wc + ((size_t)(16 + hi) * 256 + w * 64 + col) * 8;
    const ushort* wb1 = wb0 + 32 * 8;
#pragma unroll
    for (int kk = 0; kk < 12; ++kk) {        // K = 192
        const int k0 = kk * 16 + hi * 8;
        bf16x8 a0 = *(const bf16x8*)(&zt[col][k0]);
        bf16x8 a1 = *(const bf16x8*)(&zt[32 + col][k0]);
        bf16x8 b0 = *(const bf16x8*)(wb0 + (size_t)kk * 2 * 256 * 8);
        bf16x8 b1 = *(const bf16x8*)(wb1 + (size_t)kk * 2 * 256 * 8);
        acc0[0] = __builtin_amdgcn_mfma_f32_32x32x16_bf16(a0, b0, acc0[0], 0, 0, 0);
        acc1[0] = __builtin_amdgcn_mfma_f32_32x32x16_bf16(a0, b1, acc1[0], 0, 0, 0);
        acc0[1] = __builtin_amdgcn_mfma_f32_32x32x16_bf16(a1, b0, acc0[1], 0, 0, 0);
        acc1[1] = __builtin_amdgcn_mfma_f32_32x32x16_bf16(a1, b1, acc1[1], 0, 0, 0);
    }

    // epilogue: lane owns 32 edges x 1 channel (2 tiles); run-merge over sorted dsts.
    // exp(x)=exp2(x*log2e); log(1+u)=ln2*log2(1+u); 1/x via v_rcp (tolerance >> 1ulp).
    const float L2E = 1.44269504f, LN2 = 0.69314718f;
    const int ch = w * 32 + col;
    const int r0 = w * 64 + col;
    float run = 0.f;
    int prevd = s_dst[4 * hi];
    float bg = base[(size_t)prevd * 256 + r0];
    float bsv = base[(size_t)prevd * 256 + r0 + 32];
#pragma unroll
    for (int t = 0; t < 2; ++t) {
#pragma unroll
        for (int grp = 0; grp < 4; ++grp) {
            const int4 d4 = *(const int4*)(&s_dst[t * 32 + grp * 8 + 4 * hi]);
#pragma unroll
            for (int j = 0; j < 4; ++j) {
                const int q = grp * 4 + j;
                const int d = (j == 0) ? d4.x : (j == 1) ? d4.y : (j == 2) ? d4.z : d4.w;
                if (d != prevd) {
                    unsafeAtomicAdd(xnew + (size_t)prevd * C + ch, run);
                    run = 0.f;
                    prevd = d;
                    bg = base[(size_t)d * 256 + r0];
                    bsv = base[(size_t)d * 256 + r0 + 32];
                }
                float g = (t ? acc0[1][q] : acc0[0][q]) + bg;
                float s = (t ? acc1[1][q] : acc1[0][q]) + bsv;
                float gate = __builtin_amdgcn_rcpf(1.0f + __builtin_amdgcn_exp2f(-L2E * g));
                float sp = fmaf(LN2,
                                __builtin_amdgcn_logf(1.0f + __builtin_amdgcn_exp2f(-L2E * fabsf(s))),
                                fmaxf(s, 0.0f));
                run = fmaf(gate, sp, run);
            }
        }
    }
    unsafeAtomicAdd(xnew + (size_t)prevd * C + ch, run);
}

// ---------------- MLP GEMM1 (MFMA): fp32 in, h16 = bf16(x @ W1^T + b1), col stats ----------------
__global__ __launch_bounds__(256) void k_mlp1_mfma(
    const float* __restrict__ x, const ushort* __restrict__ W1T,
    const float* __restrict__ b1, ushort* __restrict__ h16,
    float* __restrict__ colsum, float* __restrict__ colsq)
{
    __shared__ ushort xs[64][136];
    const int tid = threadIdx.x;
    const int n0 = blockIdx.x * 64;
    const int ch0 = blockIdx.y * 128;
#pragma unroll
    for (int it = 0; it < 4; ++it) {
        int idx = tid + it * 256;       // 1024 chunks
        int e = idx >> 4, c = (idx & 15) * 8;
        int rr = n0 + e; if (rr >= NN) rr = NN - 1;
        const float* s = x + (size_t)rr * C + c;
        float4 u = *(const float4*)s;
        float4 v = *(const float4*)(s + 4);
        ushort o[8];
        o[0] = f2bf(u.x); o[1] = f2bf(u.y); o[2] = f2bf(u.z); o[3] = f2bf(u.w);
        o[4] = f2bf(v.x); o[5] = f2bf(v.y); o[6] = f2bf(v.z); o[7] = f2bf(v.w);
        *(uint4*)(&xs[e][c]) = *(uint4*)o;
    }
    __syncthreads();
    const int w = tid >> 6, l = tid & 63, lr = l & 15, lq = l >> 4, kp = lq * 8;
    const int cb = ch0 + w * 32;
    f32x4 acc[4][2];
#pragma unroll
    for (int rt = 0; rt < 4; ++rt) { acc[rt][0] = (f32x4){0,0,0,0}; acc[rt][1] = (f32x4){0,0,0,0}; }
    for (int kk = 0; kk < 4; ++kk) {
        int k0 = kk * 32 + kp;
        bf16x8 a[4], b[2];
#pragma unroll
        for (int rt = 0; rt < 4; ++rt) a[rt] = *(const bf16x8*)(&xs[rt * 16 + lr][k0]);
#pragma unroll
        for (int j = 0; j < 2; ++j)
            b[j] = *(const bf16x8*)(W1T + (((size_t)(kk * 4 + lq) * HD + cb + j * 16 + lr) << 3));
#pragma unroll
        for (int rt = 0; rt < 4; ++rt)
#pragma unroll
            for (int j = 0; j < 2; ++j)
                acc[rt][j] = __builtin_amdgcn_mfma_f32_16x16x32_bf16(a[rt], b[j], acc[rt][j], 0, 0, 0);
    }
    const int ro = lq * 4;
    float ps[2] = {0.f, 0.f}, pq[2] = {0.f, 0.f};
#pragma unroll
    for (int j = 0; j < 2; ++j) {
        const int ch = cb + j * 16 + lr;
        const float bv = b1[ch];
#pragma unroll
        for (int rt = 0; rt < 4; ++rt) {
#pragma unroll
            for (int q = 0; q < 4; ++q) {
                int row = n0 + rt * 16 + ro + q;
                float hv = acc[rt][j][q] + bv;
                if (row < NN) {
                    h16[(size_t)row * HD + ch] = f2bf(hv);
                    ps[j] += hv; pq[j] += hv * hv;
                }
            }
        }
    }
#pragma unroll
    for (int j = 0; j < 2; ++j) {
        ps[j] += __shfl_xor(ps[j], 16); ps[j] += __shfl_xor(ps[j], 32);
        pq[j] += __shfl_xor(pq[j], 16); pq[j] += __shfl_xor(pq[j], 32);
    }
    if (l < 16) {
#pragma unroll
        for (int j = 0; j < 2; ++j) {
            unsafeAtomicAdd(colsum + cb + j * 16 + lr, ps[j]);
            unsafeAtomicAdd(colsq + cb + j * 16 + lr, pq[j]);
        }
    }
}

// finalizes BN affine and re-zeros colsum/colsq for the next layer
__global__ void k_bnstats(float* __restrict__ colsum, float* __restrict__ colsq,
                          const float* __restrict__ g1, const float* __restrict__ be1,
                          float* __restrict__ bn_a, float* __restrict__ bn_b) {
    int c = threadIdx.x;   // 512
    float m = colsum[c] * (1.0f / NN);
    float v = colsq[c] * (1.0f / NN) - m * m;
    float istd = rsqrtf(fmaxf(v, 0.f) + EPSV);
    float a = g1[c] * istd;
    bn_a[c] = a;
    bn_b[c] = fmaf(-m, a, be1[c]);
    colsum[c] = 0.f;
    colsq[c] = 0.f;
}

// ---------------- MLP GEMM2 (MFMA): x = xres + relu(a*h+b) @ W2^T + b2 ----------------
__global__ __launch_bounds__(256) void k_mlp2_mfma(
    const ushort* __restrict__ h16, const float* __restrict__ bn_a, const float* __restrict__ bn_b,
    const ushort* __restrict__ W2T, const float* __restrict__ b2,
    const float* __restrict__ xres, float* __restrict__ xout)
{
    __shared__ ushort hs[64][136];
    const int tid = threadIdx.x;
    const int n0 = blockIdx.x * 64;
    const int w = tid >> 6, l = tid & 63, lr = l & 15, lq = l >> 4, kp = lq * 8;
    f32x4 acc[4][2];
#pragma unroll
    for (int rt = 0; rt < 4; ++rt) { acc[rt][0] = (f32x4){0,0,0,0}; acc[rt][1] = (f32x4){0,0,0,0}; }

    for (int kc = 0; kc < 4; ++kc) {
#pragma unroll
        for (int it = 0; it < 4; ++it) {
            int idx = tid + it * 256;
            int e = idx >> 4, c = (idx & 15) * 8;
            int rr = n0 + e; if (rr >= NN) rr = NN - 1;
            int k = kc * 128 + c;
            bf16x8 hv = *(const bf16x8*)(h16 + (size_t)rr * HD + k);
            ushort o[8];
#pragma unroll
            for (int m = 0; m < 8; ++m) {
                float f = bf2f((ushort)hv[m]);
                f = fmaf(bn_a[k + m], f, bn_b[k + m]);
                o[m] = f2bf(fmaxf(f, 0.f));
            }
            *(uint4*)(&hs[e][c]) = *(uint4*)o;
        }
        __syncthreads();
        for (int kk = 0; kk < 4; ++kk) {
            int k0 = kk * 32 + kp;
            bf16x8 a[4], b[2];
#pragma unroll
            for (int rt = 0; rt < 4; ++rt) a[rt] = *(const bf16x8*)(&hs[rt * 16 + lr][k0]);
#pragma unroll
            for (int j = 0; j < 2; ++j)
                b[j] = *(const bf16x8*)(W2T + (((size_t)(kc * 16 + kk * 4 + lq) * C + w * 32 + j * 16 + lr) << 3));
#pragma unroll
            for (int rt = 0; rt < 4; ++rt)
#pragma unroll
                for (int j = 0; j < 2; ++j)
                    acc[rt][j] = __builtin_amdgcn_mfma_f32_16x16x32_bf16(a[rt], b[j], acc[rt][j], 0, 0, 0);
        }
        __syncthreads();
    }
    const int ro = lq * 4;
#pragma unroll
    for (int j = 0; j < 2; ++j) {
        const int ch = w * 32 + j * 16 + lr;
        const float bv = b2[ch];
#pragma unroll
        for (int rt = 0; rt < 4; ++rt) {
#pragma unroll
            for (int q = 0; q < 4; ++q) {
                int row = n0 + rt * 16 + ro + q;
                if (row < NN)
                    xout[(size_t)row * C + ch] = xres[(size_t)row * C + ch] + acc[rt][j][q] + bv;
            }
        }
    }
}

// ---------------- graph LayerNorm stats (block-level reduce, run-merged atomics) ----------------
__global__ __launch_bounds__(256) void k_lnstats(
    const float* __restrict__ x2, const int* __restrict__ nb_arr,
    float* __restrict__ gsum, float* __restrict__ gsq)
{
    __shared__ float sh_s[64], sh_q[64];
    __shared__ int sh_g[64];
    const int tid = threadIdx.x;
    const int nl = tid >> 2;                 // node-local 0..63
    const int node = blockIdx.x * 64 + nl;
    const int sub = tid & 3;
    const int nvalid = min(64, NN - blockIdx.x * 64);
    if (node < NN) {
        const float4* row = (const float4*)(x2 + (size_t)node * C);
        float s = 0.f, q = 0.f;
#pragma unroll
        for (int t = 0; t < 8; ++t) {
            float4 v = row[sub + 4 * t];
            s += v.x + v.y + v.z + v.w;
            q += v.x * v.x + v.y * v.y + v.z * v.z + v.w * v.w;
        }
        s += __shfl_xor(s, 1); q += __shfl_xor(q, 1);
        s += __shfl_xor(s, 2); q += __shfl_xor(q, 2);
        if (sub == 0) {
            sh_s[nl] = s; sh_q[nl] = q; sh_g[nl] = nb_arr[node];
        }
    }
    __syncthreads();
    if (tid == 0) {
        int pg = sh_g[0];
        float rs = 0.f, rq = 0.f;
        for (int i = 0; i < nvalid; ++i) {
            int g = sh_g[i];
            if (g != pg) {
                unsafeAtomicAdd(&gsum[pg], rs);
                unsafeAtomicAdd(&gsq[pg], rq);
                rs = 0.f; rq = 0.f; pg = g;
            }
            rs += sh_s[i]; rq += sh_q[i];
        }
        unsafeAtomicAdd(&gsum[pg], rs);
        unsafeAtomicAdd(&gsq[pg], rq);
    }
}

// finalizes LN mean/istd and re-zeros gsum/gsq for the next layer
__global__ void k_lnfin(float* __restrict__ gsum, float* __restrict__ gsq,
                        const int* __restrict__ gcount,
                        float* __restrict__ gmean, float* __restrict__ gistd) {
    int g = threadIdx.x;
    float cnt = fmaxf((float)gcount[g], 1.0f) * (float)C;
    float m = gsum[g] / cnt;
    float v = gsq[g] / cnt - m * m;
    gmean[g] = m;
    gistd[g] = rsqrtf(fmaxf(v, 0.f) + EPSV);
    gsum[g] = 0.f;
    gsq[g] = 0.f;
}

// fused: fp32 out (+ optional bf16 copy for next edge layer + fp32 residual copy)
__global__ __launch_bounds__(256) void k_lnapply(
    const float* __restrict__ x2, const int* __restrict__ nb_arr,
    const float* __restrict__ gmean, const float* __restrict__ gistd,
    const float* __restrict__ lnw, const float* __restrict__ lnb,
    float* __restrict__ out, ushort* __restrict__ bfout, float* __restrict__ xbout, int aux)
{
    int idx = blockIdx.x * 256 + threadIdx.x;   // NC/4 threads
    int elem = idx * 4;
    int n = elem >> 7, c = elem & 127;
    int g = nb_arr[n];
    float m = gmean[g], is = gistd[g];
    float4 v = *(const float4*)(x2 + elem);
    float4 wv = *(const float4*)(lnw + c);
    float4 bv = *(const float4*)(lnb + c);
    float4 r;
    r.x = (v.x - m) * is * wv.x + bv.x;
    r.y = (v.y - m) * is * wv.y + bv.y;
    r.z = (v.z - m) * is * wv.z + bv.z;
    r.w = (v.w - m) * is * wv.w + bv.w;
    *(float4*)(out + elem) = r;
    if (aux) {
        ushort4 o;
        o.x = f2bf(r.x); o.y = f2bf(r.y); o.z = f2bf(r.z); o.w = f2bf(r.w);
        *(ushort4*)(bfout + elem) = o;
        *(float4*)(xbout + elem) = r;
    }
}

// ---------------- launcher ----------------
extern "C" void kernel_launch(void* const* d_in, const int* in_sizes, int n_in,
                              void* d_out, int out_size, void* d_ws, size_t ws_size,
                              hipStream_t stream) {
    const float* x_in = (const float*)d_in[0];
    const int* node_batch = (const int*)d_in[1];
    const int* ei = (const int*)d_in[2];
    const float* ea = (const float*)d_in[3];
    const float* Wf = (const float*)d_in[4];
    const float* bfv = (const float*)d_in[5];
    const float* Ws = (const float*)d_in[6];
    const float* bsv = (const float*)d_in[7];
    const float* W1 = (const float*)d_in[8];
    const float* b1 = (const float*)d_in[9];
    const float* g1 = (const float*)d_in[10];
    const float* be1 = (const float*)d_in[11];
    const float* W2 = (const float*)d_in[12];
    const float* b2 = (const float*)d_in[13];
    const float* lnw = (const float*)d_in[14];
    const float* lnb = (const float*)d_in[15];
    float* out = (float*)d_out;

    const size_t NC = (size_t)NN * C;       // 2,560,000
    const size_t NH = (size_t)NN * HD;      // 10,240,000
    float* p = (float*)d_ws;
    float* xa = p; p += NC;
    float* xb = p; p += NC;
    ushort* h16 = (ushort*)p; p += NH / 2;  // base[N][256] fp32 aliases this (exactly NH/2 floats)
    float* base = (float*)h16;
    ushort* bfx = (ushort*)p; p += NC / 2;
    ushort* Wce = (ushort*)p; p += 40960;          // 81920 ushorts
    ushort* W116 = (ushort*)p; p += 98304;         // 3*65536 ushorts (k-major)
    ushort* W216 = (ushort*)p; p += 98304;
    float* bc = p; p += 256;
    float* bn_a = p; p += 512;
    float* bn_b = p; p += 512;
    float* colsum = p; p += 512;
    float* colsq = p; p += 512;                    // contiguous with colsum
    float* gsum = p; p += 32;
    float* gsq = p; p += 32;                       // contiguous with gsum
    float* gmean = p; p += 32;
    float* gistd = p; p += 32;
    int* gcount = (int*)p; p += 32;
    int* deg = (int*)p; p += NN;
    int* cursor = (int*)p; p += NN;
    int* bsum = (int*)p; p += 128;
    int* boff = (int*)p; p += 128;
    int* perm = (int*)p; p += NE;
    ushort* ea16p = (ushort*)p; p += (size_t)NE * DE / 2;   // 40.96M ushorts

    const bool sea = ws_size >= (size_t)((char*)p - (char*)d_ws);
    const int NB_SCAN = (NN + 255) / 256;          // 79

    // ---- one-time per call: sort edges by dst, graph counts, weight preps ----
    hipMemsetAsync(deg, 0, NN * 4, stream);
    k_hist<<<NE / 256, 256, 0, stream>>>(ei, deg);
    k_scan1<<<NB_SCAN, 256, 0, stream>>>(deg, cursor, bsum);
    k_scan2<<<1, 1, 0, stream>>>(bsum, boff, NB_SCAN);
    k_scan3<<<NB_SCAN, 256, 0, stream>>>(cursor, boff);
    k_scatter<<<NE / 256, 256, 0, stream>>>(ei, cursor, perm);
    if (sea) k_permea<<<NE / 64, 256, 0, stream>>>(ea, perm, ea16p);

    hipMemsetAsync(gcount, 0, G * 4, stream);
    k_gcount<<<(NN + 255) / 256, 256, 0, stream>>>(node_batch, gcount);

    k_prepw1T<<<768, 256, 0, stream>>>(W1, W116);
    k_prepw2T<<<768, 256, 0, stream>>>(W2, W216);

    // stats accumulators zeroed once; producers re-zero them each layer
    hipMemsetAsync(colsum, 0, 1024 * 4, stream);
    hipMemsetAsync(gsum, 0, 64 * 4, stream);

    hipMemcpyAsync(xa, x_in, NC * 4, hipMemcpyDeviceToDevice, stream);
    hipMemcpyAsync(xb, x_in, NC * 4, hipMemcpyDeviceToDevice, stream);
    k_cast_x<<<NC / 1024, 256, 0, stream>>>(x_in, bfx);

    for (int l = 0; l < LL; ++l) {
        k_prepw32T<<<320, 256, 0, stream>>>(
            Wf + (size_t)l * C * ZD, bfv + (size_t)l * C,
            Ws + (size_t)l * C * ZD, bsv + (size_t)l * C, Wce, bc);
        k_base<<<NN / 32, 256, 0, stream>>>(bfx, Wce, bc, base);
        // xb already holds x (residual); edge accumulates messages into it
        if (sea)
            k_edge64<true><<<NE / 64, 256, 0, stream>>>(bfx, ei, perm, ea, ea16p, Wce, base, xb);
        else
            k_edge64<false><<<NE / 64, 256, 0, stream>>>(bfx, ei, perm, ea, ea16p, Wce, base, xb);

        k_mlp1_mfma<<<dim3(313, 4), 256, 0, stream>>>(xb,
            W116 + (size_t)l * 65536, b1 + (size_t)l * HD, h16, colsum, colsq);
        k_bnstats<<<1, HD, 0, stream>>>(colsum, colsq,
            g1 + (size_t)l * HD, be1 + (size_t)l * HD, bn_a, bn_b);

        k_mlp2_mfma<<<313, 256, 0, stream>>>(h16, bn_a, bn_b,
            W216 + (size_t)l * 65536, b2 + (size_t)l * C, xb, xa);

        k_lnstats<<<(NN + 63) / 64, 256, 0, stream>>>(xa, node_batch, gsum, gsq);
        k_lnfin<<<1, G, 0, stream>>>(gsum, gsq, gcount, gmean, gistd);
        float* dstp = (l == LL - 1) ? out : xa;
        k_lnapply<<<NC / 1024, 256, 0, stream>>>(xa, node_batch, gmean, gistd,
            lnw + (size_t)l * C, lnb + (size_t)l * C, dstp, bfx, xb, (l != LL - 1) ? 1 : 0);
    }
}

// Round 16
// 697.055 us; speedup vs baseline: 5.5693x; 4.8736x over previous
//
#include <hip/hip_runtime.h>
#include <hip/hip_bf16.h>
#include <math.h>

#define NN 20000
#define NE 640000
#define C 128
#define DE 64
#define ZD 320
#define HD 512
#define G 32
#define LL 3
#define EPSV 1e-5f

typedef __attribute__((ext_vector_type(8))) short bf16x8;
typedef __attribute__((ext_vector_type(4))) float f32x4;
typedef __attribute__((ext_vector_type(16))) float f32x16;

__device__ __forceinline__ ushort f2bf(float f) {
    __hip_bfloat16 h = __float2bfloat16(f);
    return *reinterpret_cast<ushort*>(&h);
}
__device__ __forceinline__ float bf2f(ushort u) {
    return __uint_as_float(((unsigned)u) << 16);
}

// ---------------- graph counting (LDS histogram -> 32 atomics/block) ----------------
__global__ __launch_bounds__(256) void k_gcount(const int* __restrict__ nb, int* __restrict__ gcount) {
    __shared__ int hist[G];
    int t = threadIdx.x;
    if (t < G) hist[t] = 0;
    __syncthreads();
    int i = blockIdx.x * 256 + t;
    if (i < NN) atomicAdd(&hist[nb[i]], 1);
    __syncthreads();
    if (t < G && hist[t] > 0) atomicAdd(&gcount[t], hist[t]);
}

// ---------------- edge sort by dst (counting sort) ----------------
__global__ __launch_bounds__(256) void k_hist(const int* __restrict__ ei, int* __restrict__ deg) {
    int e = blockIdx.x * 256 + threadIdx.x;
    atomicAdd(&deg[ei[NE + e]], 1);
}
__global__ __launch_bounds__(256) void k_scan1(const int* __restrict__ deg, int* __restrict__ cursor,
                                               int* __restrict__ bsum) {
    __shared__ int sh[256];
    int t = threadIdx.x, b = blockIdx.x, i = b * 256 + t;
    int v = (i < NN) ? deg[i] : 0;
    sh[t] = v; __syncthreads();
    for (int off = 1; off < 256; off <<= 1) {
        int u = (t >= off) ? sh[t - off] : 0;
        __syncthreads();
        sh[t] += u;
        __syncthreads();
    }
    if (i < NN) cursor[i] = sh[t] - v;
    if (t == 255) bsum[b] = sh[255];
}
__global__ void k_scan2(const int* __restrict__ bsum, int* __restrict__ boff, int nb) {
    int r = 0;
    for (int b = 0; b < nb; ++b) { boff[b] = r; r += bsum[b]; }
}
__global__ __launch_bounds__(256) void k_scan3(int* __restrict__ cursor, const int* __restrict__ boff) {
    int i = blockIdx.x * 256 + threadIdx.x;
    if (i < NN) cursor[i] += boff[blockIdx.x];
}
__global__ __launch_bounds__(256) void k_scatter(const int* __restrict__ ei, int* __restrict__ cursor,
                                                 int* __restrict__ perm) {
    int e = blockIdx.x * 256 + threadIdx.x;
    int d = ei[NE + e];
    int pos = atomicAdd(&cursor[d], 1);
    perm[pos] = e;
}

// ---------------- permute + cast edge_attr to bf16, sorted order ----------------
__global__ __launch_bounds__(256) void k_permea(const float* __restrict__ ea,
                                                const int* __restrict__ perm,
                                                ushort* __restrict__ out) {
    const int tid = threadIdx.x;
    const int e0 = blockIdx.x * 64;
#pragma unroll
    for (int it = 0; it < 4; ++it) {
        int idx = tid + it * 256;          // 1024 float4-chunks per block
        int e = idx >> 4, f4 = idx & 15;
        int p = perm[e0 + e];
        float4 v = *(const float4*)(ea + (size_t)p * DE + f4 * 4);
        ushort4 o;
        o.x = f2bf(v.x); o.y = f2bf(v.y); o.z = f2bf(v.z); o.w = f2bf(v.w);
        *(ushort4*)(out + (size_t)(e0 + e) * DE + f4 * 4) = o;
    }
}

// ---------------- casts ----------------
__global__ __launch_bounds__(256) void k_cast_x(const float* __restrict__ in, ushort* __restrict__ out) {
    int idx = blockIdx.x * 256 + threadIdx.x;    // n/4 threads
    float4 v = ((const float4*)in)[idx];
    ushort4 o;
    o.x = f2bf(v.x); o.y = f2bf(v.y); o.z = f2bf(v.z); o.w = f2bf(v.w);
    ((ushort4*)out)[idx] = o;
}

// ---------------- MLP weight transposes to k-major (one-time) ----------------
__global__ __launch_bounds__(256) void k_prepw1T(const float* __restrict__ W1, ushort* __restrict__ W1T) {
    int idx = blockIdx.x * 256 + threadIdx.x;      // 3*512*128 = 196608
    int l = idx >> 16, r = idx & 65535;
    int ch = r >> 7, k = r & 127;
    W1T[(size_t)l * 65536 + (((k >> 3) * HD + ch) << 3) + (k & 7)] = f2bf(W1[idx]);
}
__global__ __launch_bounds__(256) void k_prepw2T(const float* __restrict__ W2, ushort* __restrict__ W2T) {
    int idx = blockIdx.x * 256 + threadIdx.x;      // 3*128*512 = 196608
    int l = idx >> 16, r = idx & 65535;
    int ch = r >> 9, k = r & 511;
    W2T[(size_t)l * 65536 + (((k >> 3) * C + ch) << 3) + (k & 7)] = f2bf(W2[idx]);
}

// ---------------- build combined edge weights (bf16), k-major coalesced ----------------
__global__ __launch_bounds__(256) void k_prepw32T(
    const float* __restrict__ Wf, const float* __restrict__ bfv,
    const float* __restrict__ Ws, const float* __restrict__ bsv,
    ushort* __restrict__ Wc, float* __restrict__ bc)
{
    int idx = blockIdx.x * 256 + threadIdx.x;    // 256*320
    int r = idx / 320, k = idx - r * 320;
    int w = r >> 6, half = (r >> 5) & 1, off = r & 31;
    int ch = w * 32 + off;
    const float* W = half ? Ws : Wf;
    Wc[((size_t)(k >> 3) * 256 + r) * 8 + (k & 7)] = f2bf(W[(size_t)ch * ZD + k]);
    if (k == 0) bc[r] = (half ? bsv : bfv)[ch];
}

// ---------------- per-node base: base[n][r] = x_n @ Wc_r[0:128]^T + bc[r] ----------------
__global__ __launch_bounds__(256, 8) void k_base(
    const ushort* __restrict__ x16, const ushort* __restrict__ Wc,
    const float* __restrict__ bc, float* __restrict__ base)
{
    __shared__ ushort xs[32][136];
    const int tid = threadIdx.x;
    const int n0 = blockIdx.x * 32;          // 625 blocks x 32 nodes = 20000 exact
#pragma unroll
    for (int it = 0; it < 2; ++it) {
        int idx = tid + it * 256;            // 512 chunks (32 nodes x 16)
        int n = idx >> 4, c = (idx & 15) * 8;
        *(uint4*)(&xs[n][c]) = *(const uint4*)(x16 + (size_t)(n0 + n) * C + c);
    }
    __syncthreads();
    const int w = tid >> 6, l = tid & 63;
    const int col = l & 31, hi = l >> 5;
    f32x16 acc0, acc1;
#pragma unroll
    for (int i = 0; i < 16; ++i) { acc0[i] = 0.f; acc1[i] = 0.f; }
    const ushort* wb0 = Wc + ((size_t)hi * 256 + w * 64 + col) * 8;
    const ushort* wb1 = wb0 + 32 * 8;
#pragma unroll
    for (int kk = 0; kk < 8; ++kk) {         // K = 128 (x section, chunks 0..15)
        const int k0 = kk * 16 + hi * 8;
        bf16x8 a = *(const bf16x8*)(&xs[col][k0]);
        bf16x8 b0 = *(const bf16x8*)(wb0 + (size_t)kk * 2 * 256 * 8);
        bf16x8 b1 = *(const bf16x8*)(wb1 + (size_t)kk * 2 * 256 * 8);
        acc0 = __builtin_amdgcn_mfma_f32_32x32x16_bf16(a, b0, acc0, 0, 0, 0);
        acc1 = __builtin_amdgcn_mfma_f32_32x32x16_bf16(a, b1, acc1, 0, 0, 0);
    }
    const int r0 = w * 64 + col;
    const float bg = bc[r0], bs = bc[r0 + 32];
#pragma unroll
    for (int q = 0; q < 16; ++q) {
        int nl = (q & 3) + 8 * (q >> 2) + 4 * hi;
        float* brow = base + (size_t)(n0 + nl) * 256;
        brow[r0] = acc0[q] + bg;
        brow[r0 + 32] = acc1[q] + bs;
    }
}

// ---------------- CGConv edge kernel: 64 edges/block, K=192, shared B-frags ----------------
// Epilogue: exp2/log2/rcp forms (no IEEE div, no libm const-muls), int4 dst loads.
// launch_bounds(256,5): VGPR 48 (4x f32x16 accs need 64+; DO NOT tighten — r15 spilled at 6).
template<bool SEA>
__global__ __launch_bounds__(256, 5) void k_edge64(
    const ushort* __restrict__ x16, const int* __restrict__ ei,
    const int* __restrict__ perm, const float* __restrict__ ea,
    const ushort* __restrict__ ea16p, const ushort* __restrict__ Wc,
    const float* __restrict__ base, float* __restrict__ xnew)
{
    __shared__ ushort zt[64][200];           // 192 + 8 pad
    __shared__ __align__(16) int s_dst[64];
    __shared__ int s_src[64], s_perm[64];
    const int tid = threadIdx.x;
    const int bid = blockIdx.x;
    const int swz = (bid & 7) * (NE / 64 / 8) + (bid >> 3);   // bijective: 10000 % 8 == 0
    const int e0 = swz * 64;
    if (tid < 64) {
        int p = perm[e0 + tid];
        s_perm[tid] = p;
        s_src[tid] = ei[p];
        s_dst[tid] = ei[NE + p];
    }
    __syncthreads();

    // gather x_src: 64 edges x 16 chunks = 1024, shift/mask only
#pragma unroll
    for (int it = 0; it < 4; ++it) {
        int idx = tid + it * 256;
        int e = idx >> 4, r = idx & 15;
        *(uint4*)(&zt[e][r * 8]) = *(const uint4*)(x16 + (size_t)s_src[e] * C + r * 8);
    }
    // gather ea: 64 edges x 8 chunks = 512
    if (SEA) {
#pragma unroll
        for (int it = 0; it < 2; ++it) {
            int idx = tid + it * 256;
            int e = idx >> 3, r = idx & 7;
            *(uint4*)(&zt[e][128 + r * 8]) =
                *(const uint4*)(ea16p + (size_t)(e0 + e) * DE + r * 8);
        }
    } else {
#pragma unroll
        for (int it = 0; it < 2; ++it) {
            int idx = tid + it * 256;
            int e = idx >> 3, r = idx & 7;
            const float* s = ea + (size_t)s_perm[e] * DE + r * 8;
            float4 u = *(const float4*)s;
            float4 v = *(const float4*)(s + 4);
            ushort o[8];
            o[0] = f2bf(u.x); o[1] = f2bf(u.y); o[2] = f2bf(u.z); o[3] = f2bf(u.w);
            o[4] = f2bf(v.x); o[5] = f2bf(v.y); o[6] = f2bf(v.z); o[7] = f2bf(v.w);
            *(uint4*)(&zt[e][128 + r * 8]) = *(uint4*)o;
        }
    }
    __syncthreads();

    const int w = tid >> 6, l = tid & 63;
    const int col = l & 31;
    const int hi = l >> 5;
    f32x16 acc0[2], acc1[2];                 // [edge-tile][gate/softplus]
#pragma unroll
    for (int i = 0; i < 16; ++i) {
        acc0[0][i] = 0.f; acc1[0][i] = 0.f; acc0[1][i] = 0.f; acc1[1][i] = 0.f;
    }

    // K-global = 128 + kk*16 + hi*8 -> chunk = 16 + kk*2 + hi
    const ushort* wb0 = Wc + ((size_t)(16 + hi) * 256 + w * 64 + col) * 8;
    const ushort* wb1 = wb0 + 32 * 8;
#pragma unroll
    for (int kk = 0; kk < 12; ++kk) {        // K = 192
        const int k0 = kk * 16 + hi * 8;
        bf16x8 a0 = *(const bf16x8*)(&zt[col][k0]);
        bf16x8 a1 = *(const bf16x8*)(&zt[32 + col][k0]);
        bf16x8 b0 = *(const bf16x8*)(wb0 + (size_t)kk * 2 * 256 * 8);
        bf16x8 b1 = *(const bf16x8*)(wb1 + (size_t)kk * 2 * 256 * 8);
        acc0[0] = __builtin_amdgcn_mfma_f32_32x32x16_bf16(a0, b0, acc0[0], 0, 0, 0);
        acc1[0] = __builtin_amdgcn_mfma_f32_32x32x16_bf16(a0, b1, acc1[0], 0, 0, 0);
        acc0[1] = __builtin_amdgcn_mfma_f32_32x32x16_bf16(a1, b0, acc0[1], 0, 0, 0);
        acc1[1] = __builtin_amdgcn_mfma_f32_32x32x16_bf16(a1, b1, acc1[1], 0, 0, 0);
    }

    // epilogue: lane owns 32 edges x 1 channel (2 tiles); run-merge over sorted dsts.
    // exp(x)=exp2(x*log2e); log(1+u)=ln2*log2(1+u); 1/x via v_rcp (tolerance >> 1ulp).
    const float L2E = 1.44269504f, LN2 = 0.69314718f;
    const int ch = w * 32 + col;
    const int r0 = w * 64 + col;
    float run = 0.f;
    int prevd = s_dst[4 * hi];
    float bg = base[(size_t)prevd * 256 + r0];
    float bsv = base[(size_t)prevd * 256 + r0 + 32];
#pragma unroll
    for (int t = 0; t < 2; ++t) {
#pragma unroll
        for (int grp = 0; grp < 4; ++grp) {
            const int4 d4 = *(const int4*)(&s_dst[t * 32 + grp * 8 + 4 * hi]);
#pragma unroll
            for (int j = 0; j < 4; ++j) {
                const int q = grp * 4 + j;
                const int d = (j == 0) ? d4.x : (j == 1) ? d4.y : (j == 2) ? d4.z : d4.w;
                if (d != prevd) {
                    unsafeAtomicAdd(xnew + (size_t)prevd * C + ch, run);
                    run = 0.f;
                    prevd = d;
                    bg = base[(size_t)d * 256 + r0];
                    bsv = base[(size_t)d * 256 + r0 + 32];
                }
                float g = (t ? acc0[1][q] : acc0[0][q]) + bg;
                float s = (t ? acc1[1][q] : acc1[0][q]) + bsv;
                float gate = __builtin_amdgcn_rcpf(1.0f + __builtin_amdgcn_exp2f(-L2E * g));
                float sp = fmaf(LN2,
                                __builtin_amdgcn_logf(1.0f + __builtin_amdgcn_exp2f(-L2E * fabsf(s))),
                                fmaxf(s, 0.0f));
                run = fmaf(gate, sp, run);
            }
        }
    }
    unsafeAtomicAdd(xnew + (size_t)prevd * C + ch, run);
}

// ---------------- MLP GEMM1 (MFMA): fp32 in, h16 = bf16(x @ W1^T + b1), col stats ----------------
__global__ __launch_bounds__(256) void k_mlp1_mfma(
    const float* __restrict__ x, const ushort* __restrict__ W1T,
    const float* __restrict__ b1, ushort* __restrict__ h16,
    float* __restrict__ colsum, float* __restrict__ colsq)
{
    __shared__ ushort xs[64][136];
    const int tid = threadIdx.x;
    const int n0 = blockIdx.x * 64;
    const int ch0 = blockIdx.y * 128;
#pragma unroll
    for (int it = 0; it < 4; ++it) {
        int idx = tid + it * 256;       // 1024 chunks
        int e = idx >> 4, c = (idx & 15) * 8;
        int rr = n0 + e; if (rr >= NN) rr = NN - 1;
        const float* s = x + (size_t)rr * C + c;
        float4 u = *(const float4*)s;
        float4 v = *(const float4*)(s + 4);
        ushort o[8];
        o[0] = f2bf(u.x); o[1] = f2bf(u.y); o[2] = f2bf(u.z); o[3] = f2bf(u.w);
        o[4] = f2bf(v.x); o[5] = f2bf(v.y); o[6] = f2bf(v.z); o[7] = f2bf(v.w);
        *(uint4*)(&xs[e][c]) = *(uint4*)o;
    }
    __syncthreads();
    const int w = tid >> 6, l = tid & 63, lr = l & 15, lq = l >> 4, kp = lq * 8;
    const int cb = ch0 + w * 32;
    f32x4 acc[4][2];
#pragma unroll
    for (int rt = 0; rt < 4; ++rt) { acc[rt][0] = (f32x4){0,0,0,0}; acc[rt][1] = (f32x4){0,0,0,0}; }
    for (int kk = 0; kk < 4; ++kk) {
        int k0 = kk * 32 + kp;
        bf16x8 a[4], b[2];
#pragma unroll
        for (int rt = 0; rt < 4; ++rt) a[rt] = *(const bf16x8*)(&xs[rt * 16 + lr][k0]);
#pragma unroll
        for (int j = 0; j < 2; ++j)
            b[j] = *(const bf16x8*)(W1T + (((size_t)(kk * 4 + lq) * HD + cb + j * 16 + lr) << 3));
#pragma unroll
        for (int rt = 0; rt < 4; ++rt)
#pragma unroll
            for (int j = 0; j < 2; ++j)
                acc[rt][j] = __builtin_amdgcn_mfma_f32_16x16x32_bf16(a[rt], b[j], acc[rt][j], 0, 0, 0);
    }
    const int ro = lq * 4;
    float ps[2] = {0.f, 0.f}, pq[2] = {0.f, 0.f};
#pragma unroll
    for (int j = 0; j < 2; ++j) {
        const int ch = cb + j * 16 + lr;
        const float bv = b1[ch];
#pragma unroll
        for (int rt = 0; rt < 4; ++rt) {
#pragma unroll
            for (int q = 0; q < 4; ++q) {
                int row = n0 + rt * 16 + ro + q;
                float hv = acc[rt][j][q] + bv;
                if (row < NN) {
                    h16[(size_t)row * HD + ch] = f2bf(hv);
                    ps[j] += hv; pq[j] += hv * hv;
                }
            }
        }
    }
#pragma unroll
    for (int j = 0; j < 2; ++j) {
        ps[j] += __shfl_xor(ps[j], 16); ps[j] += __shfl_xor(ps[j], 32);
        pq[j] += __shfl_xor(pq[j], 16); pq[j] += __shfl_xor(pq[j], 32);
    }
    if (l < 16) {
#pragma unroll
        for (int j = 0; j < 2; ++j) {
            unsafeAtomicAdd(colsum + cb + j * 16 + lr, ps[j]);
            unsafeAtomicAdd(colsq + cb + j * 16 + lr, pq[j]);
        }
    }
}

// finalizes BN affine and re-zeros colsum/colsq for the next layer
__global__ void k_bnstats(float* __restrict__ colsum, float* __restrict__ colsq,
                          const float* __restrict__ g1, const float* __restrict__ be1,
                          float* __restrict__ bn_a, float* __restrict__ bn_b) {
    int c = threadIdx.x;   // 512
    float m = colsum[c] * (1.0f / NN);
    float v = colsq[c] * (1.0f / NN) - m * m;
    float istd = rsqrtf(fmaxf(v, 0.f) + EPSV);
    float a = g1[c] * istd;
    bn_a[c] = a;
    bn_b[c] = fmaf(-m, a, be1[c]);
    colsum[c] = 0.f;
    colsq[c] = 0.f;
}

// ---------------- MLP GEMM2 (MFMA): x = xres + relu(a*h+b) @ W2^T + b2 ----------------
__global__ __launch_bounds__(256) void k_mlp2_mfma(
    const ushort* __restrict__ h16, const float* __restrict__ bn_a, const float* __restrict__ bn_b,
    const ushort* __restrict__ W2T, const float* __restrict__ b2,
    const float* __restrict__ xres, float* __restrict__ xout)
{
    __shared__ ushort hs[64][136];
    const int tid = threadIdx.x;
    const int n0 = blockIdx.x * 64;
    const int w = tid >> 6, l = tid & 63, lr = l & 15, lq = l >> 4, kp = lq * 8;
    f32x4 acc[4][2];
#pragma unroll
    for (int rt = 0; rt < 4; ++rt) { acc[rt][0] = (f32x4){0,0,0,0}; acc[rt][1] = (f32x4){0,0,0,0}; }

    for (int kc = 0; kc < 4; ++kc) {
#pragma unroll
        for (int it = 0; it < 4; ++it) {
            int idx = tid + it * 256;
            int e = idx >> 4, c = (idx & 15) * 8;
            int rr = n0 + e; if (rr >= NN) rr = NN - 1;
            int k = kc * 128 + c;
            bf16x8 hv = *(const bf16x8*)(h16 + (size_t)rr * HD + k);
            ushort o[8];
#pragma unroll
            for (int m = 0; m < 8; ++m) {
                float f = bf2f((ushort)hv[m]);
                f = fmaf(bn_a[k + m], f, bn_b[k + m]);
                o[m] = f2bf(fmaxf(f, 0.f));
            }
            *(uint4*)(&hs[e][c]) = *(uint4*)o;
        }
        __syncthreads();
        for (int kk = 0; kk < 4; ++kk) {
            int k0 = kk * 32 + kp;
            bf16x8 a[4], b[2];
#pragma unroll
            for (int rt = 0; rt < 4; ++rt) a[rt] = *(const bf16x8*)(&hs[rt * 16 + lr][k0]);
#pragma unroll
            for (int j = 0; j < 2; ++j)
                b[j] = *(const bf16x8*)(W2T + (((size_t)(kc * 16 + kk * 4 + lq) * C + w * 32 + j * 16 + lr) << 3));
#pragma unroll
            for (int rt = 0; rt < 4; ++rt)
#pragma unroll
                for (int j = 0; j < 2; ++j)
                    acc[rt][j] = __builtin_amdgcn_mfma_f32_16x16x32_bf16(a[rt], b[j], acc[rt][j], 0, 0, 0);
        }
        __syncthreads();
    }
    const int ro = lq * 4;
#pragma unroll
    for (int j = 0; j < 2; ++j) {
        const int ch = w * 32 + j * 16 + lr;
        const float bv = b2[ch];
#pragma unroll
        for (int rt = 0; rt < 4; ++rt) {
#pragma unroll
            for (int q = 0; q < 4; ++q) {
                int row = n0 + rt * 16 + ro + q;
                if (row < NN)
                    xout[(size_t)row * C + ch] = xres[(size_t)row * C + ch] + acc[rt][j][q] + bv;
            }
        }
    }
}

// ---------------- graph LayerNorm stats (block-level reduce, run-merged atomics) ----------------
__global__ __launch_bounds__(256) void k_lnstats(
    const float* __restrict__ x2, const int* __restrict__ nb_arr,
    float* __restrict__ gsum, float* __restrict__ gsq)
{
    __shared__ float sh_s[64], sh_q[64];
    __shared__ int sh_g[64];
    const int tid = threadIdx.x;
    const int nl = tid >> 2;                 // node-local 0..63
    const int node = blockIdx.x * 64 + nl;
    const int sub = tid & 3;
    const int nvalid = min(64, NN - blockIdx.x * 64);
    if (node < NN) {
        const float4* row = (const float4*)(x2 + (size_t)node * C);
        float s = 0.f, q = 0.f;
#pragma unroll
        for (int t = 0; t < 8; ++t) {
            float4 v = row[sub + 4 * t];
            s += v.x + v.y + v.z + v.w;
            q += v.x * v.x + v.y * v.y + v.z * v.z + v.w * v.w;
        }
        s += __shfl_xor(s, 1); q += __shfl_xor(q, 1);
        s += __shfl_xor(s, 2); q += __shfl_xor(q, 2);
        if (sub == 0) {
            sh_s[nl] = s; sh_q[nl] = q; sh_g[nl] = nb_arr[node];
        }
    }
    __syncthreads();
    if (tid == 0) {
        int pg = sh_g[0];
        float rs = 0.f, rq = 0.f;
        for (int i = 0; i < nvalid; ++i) {
            int g = sh_g[i];
            if (g != pg) {
                unsafeAtomicAdd(&gsum[pg], rs);
                unsafeAtomicAdd(&gsq[pg], rq);
                rs = 0.f; rq = 0.f; pg = g;
            }
            rs += sh_s[i]; rq += sh_q[i];
        }
        unsafeAtomicAdd(&gsum[pg], rs);
        unsafeAtomicAdd(&gsq[pg], rq);
    }
}

// finalizes LN mean/istd and re-zeros gsum/gsq for the next layer
__global__ void k_lnfin(float* __restrict__ gsum, float* __restrict__ gsq,
                        const int* __restrict__ gcount,
                        float* __restrict__ gmean, float* __restrict__ gistd) {
    int g = threadIdx.x;
    float cnt = fmaxf((float)gcount[g], 1.0f) * (float)C;
    float m = gsum[g] / cnt;
    float v = gsq[g] / cnt - m * m;
    gmean[g] = m;
    gistd[g] = rsqrtf(fmaxf(v, 0.f) + EPSV);
    gsum[g] = 0.f;
    gsq[g] = 0.f;
}

// fused: fp32 out (+ optional bf16 copy for next edge layer + fp32 residual copy)
__global__ __launch_bounds__(256) void k_lnapply(
    const float* __restrict__ x2, const int* __restrict__ nb_arr,
    const float* __restrict__ gmean, const float* __restrict__ gistd,
    const float* __restrict__ lnw, const float* __restrict__ lnb,
    float* __restrict__ out, ushort* __restrict__ bfout, float* __restrict__ xbout, int aux)
{
    int idx = blockIdx.x * 256 + threadIdx.x;   // NC/4 threads
    int elem = idx * 4;
    int n = elem >> 7, c = elem & 127;
    int g = nb_arr[n];
    float m = gmean[g], is = gistd[g];
    float4 v = *(const float4*)(x2 + elem);
    float4 wv = *(const float4*)(lnw + c);
    float4 bv = *(const float4*)(lnb + c);
    float4 r;
    r.x = (v.x - m) * is * wv.x + bv.x;
    r.y = (v.y - m) * is * wv.y + bv.y;
    r.z = (v.z - m) * is * wv.z + bv.z;
    r.w = (v.w - m) * is * wv.w + bv.w;
    *(float4*)(out + elem) = r;
    if (aux) {
        ushort4 o;
        o.x = f2bf(r.x); o.y = f2bf(r.y); o.z = f2bf(r.z); o.w = f2bf(r.w);
        *(ushort4*)(bfout + elem) = o;
        *(float4*)(xbout + elem) = r;
    }
}

// ---------------- launcher ----------------
extern "C" void kernel_launch(void* const* d_in, const int* in_sizes, int n_in,
                              void* d_out, int out_size, void* d_ws, size_t ws_size,
                              hipStream_t stream) {
    const float* x_in = (const float*)d_in[0];
    const int* node_batch = (const int*)d_in[1];
    const int* ei = (const int*)d_in[2];
    const float* ea = (const float*)d_in[3];
    const float* Wf = (const float*)d_in[4];
    const float* bfv = (const float*)d_in[5];
    const float* Ws = (const float*)d_in[6];
    const float* bsv = (const float*)d_in[7];
    const float* W1 = (const float*)d_in[8];
    const float* b1 = (const float*)d_in[9];
    const float* g1 = (const float*)d_in[10];
    const float* be1 = (const float*)d_in[11];
    const float* W2 = (const float*)d_in[12];
    const float* b2 = (const float*)d_in[13];
    const float* lnw = (const float*)d_in[14];
    const float* lnb = (const float*)d_in[15];
    float* out = (float*)d_out;

    const size_t NC = (size_t)NN * C;       // 2,560,000
    const size_t NH = (size_t)NN * HD;      // 10,240,000
    float* p = (float*)d_ws;
    float* xa = p; p += NC;
    float* xb = p; p += NC;
    ushort* h16 = (ushort*)p; p += NH / 2;  // base[N][256] fp32 aliases this (exactly NH/2 floats)
    float* base = (float*)h16;
    ushort* bfx = (ushort*)p; p += NC / 2;
    ushort* Wce = (ushort*)p; p += 40960;          // 81920 ushorts
    ushort* W116 = (ushort*)p; p += 98304;         // 3*65536 ushorts (k-major)
    ushort* W216 = (ushort*)p; p += 98304;
    float* bc = p; p += 256;
    float* bn_a = p; p += 512;
    float* bn_b = p; p += 512;
    float* colsum = p; p += 512;
    float* colsq = p; p += 512;                    // contiguous with colsum
    float* gsum = p; p += 32;
    float* gsq = p; p += 32;                       // contiguous with gsum
    float* gmean = p; p += 32;
    float* gistd = p; p += 32;
    int* gcount = (int*)p; p += 32;
    int* deg = (int*)p; p += NN;
    int* cursor = (int*)p; p += NN;
    int* bsum = (int*)p; p += 128;
    int* boff = (int*)p; p += 128;
    int* perm = (int*)p; p += NE;
    ushort* ea16p = (ushort*)p; p += (size_t)NE * DE / 2;   // 40.96M ushorts

    const bool sea = ws_size >= (size_t)((char*)p - (char*)d_ws);
    const int NB_SCAN = (NN + 255) / 256;          // 79

    // ---- one-time per call: sort edges by dst, graph counts, weight preps ----
    hipMemsetAsync(deg, 0, NN * 4, stream);
    k_hist<<<NE / 256, 256, 0, stream>>>(ei, deg);
    k_scan1<<<NB_SCAN, 256, 0, stream>>>(deg, cursor, bsum);
    k_scan2<<<1, 1, 0, stream>>>(bsum, boff, NB_SCAN);
    k_scan3<<<NB_SCAN, 256, 0, stream>>>(cursor, boff);
    k_scatter<<<NE / 256, 256, 0, stream>>>(ei, cursor, perm);
    if (sea) k_permea<<<NE / 64, 256, 0, stream>>>(ea, perm, ea16p);

    hipMemsetAsync(gcount, 0, G * 4, stream);
    k_gcount<<<(NN + 255) / 256, 256, 0, stream>>>(node_batch, gcount);

    k_prepw1T<<<768, 256, 0, stream>>>(W1, W116);
    k_prepw2T<<<768, 256, 0, stream>>>(W2, W216);

    // stats accumulators zeroed once; producers re-zero them each layer
    hipMemsetAsync(colsum, 0, 1024 * 4, stream);
    hipMemsetAsync(gsum, 0, 64 * 4, stream);

    hipMemcpyAsync(xa, x_in, NC * 4, hipMemcpyDeviceToDevice, stream);
    hipMemcpyAsync(xb, x_in, NC * 4, hipMemcpyDeviceToDevice, stream);
    k_cast_x<<<NC / 1024, 256, 0, stream>>>(x_in, bfx);

    for (int l = 0; l < LL; ++l) {
        k_prepw32T<<<320, 256, 0, stream>>>(
            Wf + (size_t)l * C * ZD, bfv + (size_t)l * C,
            Ws + (size_t)l * C * ZD, bsv + (size_t)l * C, Wce, bc);
        k_base<<<NN / 32, 256, 0, stream>>>(bfx, Wce, bc, base);
        // xb already holds x (residual); edge accumulates messages into it
        if (sea)
            k_edge64<true><<<NE / 64, 256, 0, stream>>>(bfx, ei, perm, ea, ea16p, Wce, base, xb);
        else
            k_edge64<false><<<NE / 64, 256, 0, stream>>>(bfx, ei, perm, ea, ea16p, Wce, base, xb);

        k_mlp1_mfma<<<dim3(313, 4), 256, 0, stream>>>(xb,
            W116 + (size_t)l * 65536, b1 + (size_t)l * HD, h16, colsum, colsq);
        k_bnstats<<<1, HD, 0, stream>>>(colsum, colsq,
            g1 + (size_t)l * HD, be1 + (size_t)l * HD, bn_a, bn_b);

        k_mlp2_mfma<<<313, 256, 0, stream>>>(h16, bn_a, bn_b,
            W216 + (size_t)l * 65536, b2 + (size_t)l * C, xb, xa);

        k_lnstats<<<(NN + 63) / 64, 256, 0, stream>>>(xa, node_batch, gsum, gsq);
        k_lnfin<<<1, G, 0, stream>>>(gsum, gsq, gcount, gmean, gistd);
        float* dstp = (l == LL - 1) ? out : xa;
        k_lnapply<<<NC / 1024, 256, 0, stream>>>(xa, node_batch, gmean, gistd,
            lnw + (size_t)l * C, lnb + (size_t)l * C, dstp, bfx, xb, (l != LL - 1) ? 1 : 0);
    }
}

// Round 17
// 675.846 us; speedup vs baseline: 5.7440x; 1.0314x over previous
//
#include <hip/hip_runtime.h>
#include <hip/hip_bf16.h>
#include <math.h>

#define NN 20000
#define NE 640000
#define C 128
#define DE 64
#define ZD 320
#define HD 512
#define G 32
#define LL 3
#define EPSV 1e-5f

typedef __attribute__((ext_vector_type(8))) short bf16x8;
typedef __attribute__((ext_vector_type(4))) float f32x4;
typedef __attribute__((ext_vector_type(16))) float f32x16;

__device__ __forceinline__ ushort f2bf(float f) {
    __hip_bfloat16 h = __float2bfloat16(f);
    return *reinterpret_cast<ushort*>(&h);
}
__device__ __forceinline__ float bf2f(ushort u) {
    return __uint_as_float(((unsigned)u) << 16);
}

// ---------------- graph counting (LDS histogram -> 32 atomics/block) ----------------
__global__ __launch_bounds__(256) void k_gcount(const int* __restrict__ nb, int* __restrict__ gcount) {
    __shared__ int hist[G];
    int t = threadIdx.x;
    if (t < G) hist[t] = 0;
    __syncthreads();
    int i = blockIdx.x * 256 + t;
    if (i < NN) atomicAdd(&hist[nb[i]], 1);
    __syncthreads();
    if (t < G && hist[t] > 0) atomicAdd(&gcount[t], hist[t]);
}

// ---------------- edge sort by dst (counting sort) ----------------
__global__ __launch_bounds__(256) void k_hist(const int* __restrict__ ei, int* __restrict__ deg) {
    int e = blockIdx.x * 256 + threadIdx.x;
    atomicAdd(&deg[ei[NE + e]], 1);
}
__global__ __launch_bounds__(256) void k_scan1(const int* __restrict__ deg, int* __restrict__ cursor,
                                               int* __restrict__ bsum) {
    __shared__ int sh[256];
    int t = threadIdx.x, b = blockIdx.x, i = b * 256 + t;
    int v = (i < NN) ? deg[i] : 0;
    sh[t] = v; __syncthreads();
    for (int off = 1; off < 256; off <<= 1) {
        int u = (t >= off) ? sh[t - off] : 0;
        __syncthreads();
        sh[t] += u;
        __syncthreads();
    }
    if (i < NN) cursor[i] = sh[t] - v;
    if (t == 255) bsum[b] = sh[255];
}
__global__ void k_scan2(const int* __restrict__ bsum, int* __restrict__ boff, int nb) {
    int r = 0;
    for (int b = 0; b < nb; ++b) { boff[b] = r; r += bsum[b]; }
}
__global__ __launch_bounds__(256) void k_scan3(int* __restrict__ cursor, const int* __restrict__ boff) {
    int i = blockIdx.x * 256 + threadIdx.x;
    if (i < NN) cursor[i] += boff[blockIdx.x];
}
__global__ __launch_bounds__(256) void k_scatter(const int* __restrict__ ei, int* __restrict__ cursor,
                                                 int* __restrict__ perm) {
    int e = blockIdx.x * 256 + threadIdx.x;
    int d = ei[NE + e];
    int pos = atomicAdd(&cursor[d], 1);
    perm[pos] = e;
}

// ---------------- permute + cast edge_attr to bf16, sorted order ----------------
__global__ __launch_bounds__(256) void k_permea(const float* __restrict__ ea,
                                                const int* __restrict__ perm,
                                                ushort* __restrict__ out) {
    const int tid = threadIdx.x;
    const int e0 = blockIdx.x * 64;
#pragma unroll
    for (int it = 0; it < 4; ++it) {
        int idx = tid + it * 256;          // 1024 float4-chunks per block
        int e = idx >> 4, f4 = idx & 15;
        int p = perm[e0 + e];
        float4 v = *(const float4*)(ea + (size_t)p * DE + f4 * 4);
        ushort4 o;
        o.x = f2bf(v.x); o.y = f2bf(v.y); o.z = f2bf(v.z); o.w = f2bf(v.w);
        *(ushort4*)(out + (size_t)(e0 + e) * DE + f4 * 4) = o;
    }
}

// ---------------- casts ----------------
__global__ __launch_bounds__(256) void k_cast_x(const float* __restrict__ in, ushort* __restrict__ out) {
    int idx = blockIdx.x * 256 + threadIdx.x;    // n/4 threads
    float4 v = ((const float4*)in)[idx];
    ushort4 o;
    o.x = f2bf(v.x); o.y = f2bf(v.y); o.z = f2bf(v.z); o.w = f2bf(v.w);
    ((ushort4*)out)[idx] = o;
}

// ---------------- MLP weight transposes to k-major (one-time) ----------------
__global__ __launch_bounds__(256) void k_prepw1T(const float* __restrict__ W1, ushort* __restrict__ W1T) {
    int idx = blockIdx.x * 256 + threadIdx.x;      // 3*512*128 = 196608
    int l = idx >> 16, r = idx & 65535;
    int ch = r >> 7, k = r & 127;
    W1T[(size_t)l * 65536 + (((k >> 3) * HD + ch) << 3) + (k & 7)] = f2bf(W1[idx]);
}
__global__ __launch_bounds__(256) void k_prepw2T(const float* __restrict__ W2, ushort* __restrict__ W2T) {
    int idx = blockIdx.x * 256 + threadIdx.x;      // 3*128*512 = 196608
    int l = idx >> 16, r = idx & 65535;
    int ch = r >> 9, k = r & 511;
    W2T[(size_t)l * 65536 + (((k >> 3) * C + ch) << 3) + (k & 7)] = f2bf(W2[idx]);
}

// ---------------- build combined edge weights (bf16), k-major coalesced ----------------
__global__ __launch_bounds__(256) void k_prepw32T(
    const float* __restrict__ Wf, const float* __restrict__ bfv,
    const float* __restrict__ Ws, const float* __restrict__ bsv,
    ushort* __restrict__ Wc, float* __restrict__ bc)
{
    int idx = blockIdx.x * 256 + threadIdx.x;    // 256*320
    int r = idx / 320, k = idx - r * 320;
    int w = r >> 6, half = (r >> 5) & 1, off = r & 31;
    int ch = w * 32 + off;
    const float* W = half ? Ws : Wf;
    Wc[((size_t)(k >> 3) * 256 + r) * 8 + (k & 7)] = f2bf(W[(size_t)ch * ZD + k]);
    if (k == 0) bc[r] = (half ? bsv : bfv)[ch];
}

// ---------------- per-node base: base[n][r] = x_n @ Wc_r[0:128]^T + bc[r] ----------------
__global__ __launch_bounds__(256, 8) void k_base(
    const ushort* __restrict__ x16, const ushort* __restrict__ Wc,
    const float* __restrict__ bc, float* __restrict__ base)
{
    __shared__ ushort xs[32][136];
    const int tid = threadIdx.x;
    const int n0 = blockIdx.x * 32;          // 625 blocks x 32 nodes = 20000 exact
#pragma unroll
    for (int it = 0; it < 2; ++it) {
        int idx = tid + it * 256;            // 512 chunks (32 nodes x 16)
        int n = idx >> 4, c = (idx & 15) * 8;
        *(uint4*)(&xs[n][c]) = *(const uint4*)(x16 + (size_t)(n0 + n) * C + c);
    }
    __syncthreads();
    const int w = tid >> 6, l = tid & 63;
    const int col = l & 31, hi = l >> 5;
    f32x16 acc0, acc1;
#pragma unroll
    for (int i = 0; i < 16; ++i) { acc0[i] = 0.f; acc1[i] = 0.f; }
    const ushort* wb0 = Wc + ((size_t)hi * 256 + w * 64 + col) * 8;
    const ushort* wb1 = wb0 + 32 * 8;
#pragma unroll
    for (int kk = 0; kk < 8; ++kk) {         // K = 128 (x section, chunks 0..15)
        const int k0 = kk * 16 + hi * 8;
        bf16x8 a = *(const bf16x8*)(&xs[col][k0]);
        bf16x8 b0 = *(const bf16x8*)(wb0 + (size_t)kk * 2 * 256 * 8);
        bf16x8 b1 = *(const bf16x8*)(wb1 + (size_t)kk * 2 * 256 * 8);
        acc0 = __builtin_amdgcn_mfma_f32_32x32x16_bf16(a, b0, acc0, 0, 0, 0);
        acc1 = __builtin_amdgcn_mfma_f32_32x32x16_bf16(a, b1, acc1, 0, 0, 0);
    }
    const int r0 = w * 64 + col;
    const float bg = bc[r0], bs = bc[r0 + 32];
#pragma unroll
    for (int q = 0; q < 16; ++q) {
        int nl = (q & 3) + 8 * (q >> 2) + 4 * hi;
        float* brow = base + (size_t)(n0 + nl) * 256;
        brow[r0] = acc0[q] + bg;
        brow[r0 + 32] = acc1[q] + bs;
    }
}

// ---------------- CGConv edge kernel: 64 edges/block, K=192, shared B-frags ----------------
// launch_bounds(256,5): VGPR 48 + 64 acc (DO NOT tighten — r15 spilled at 6).
template<bool SEA>
__global__ __launch_bounds__(256, 5) void k_edge64(
    const ushort* __restrict__ x16, const int* __restrict__ ei,
    const int* __restrict__ perm, const float* __restrict__ ea,
    const ushort* __restrict__ ea16p, const ushort* __restrict__ Wc,
    const float* __restrict__ base, float* __restrict__ xnew)
{
    __shared__ ushort zt[64][200];           // 192 + 8 pad
    __shared__ __align__(16) int s_dst[64];
    __shared__ int s_src[64], s_perm[64];
    const int tid = threadIdx.x;
    const int bid = blockIdx.x;
    const int swz = (bid & 7) * (NE / 64 / 8) + (bid >> 3);   // bijective: 10000 % 8 == 0
    const int e0 = swz * 64;
    if (tid < 64) {
        int p = perm[e0 + tid];
        s_perm[tid] = p;
        s_src[tid] = ei[p];
        s_dst[tid] = ei[NE + p];
    }
    __syncthreads();

    // gather x_src: 64 edges x 16 chunks = 1024, shift/mask only
#pragma unroll
    for (int it = 0; it < 4; ++it) {
        int idx = tid + it * 256;
        int e = idx >> 4, r = idx & 15;
        *(uint4*)(&zt[e][r * 8]) = *(const uint4*)(x16 + (size_t)s_src[e] * C + r * 8);
    }
    // gather ea: 64 edges x 8 chunks = 512
    if (SEA) {
#pragma unroll
        for (int it = 0; it < 2; ++it) {
            int idx = tid + it * 256;
            int e = idx >> 3, r = idx & 7;
            *(uint4*)(&zt[e][128 + r * 8]) =
                *(const uint4*)(ea16p + (size_t)(e0 + e) * DE + r * 8);
        }
    } else {
#pragma unroll
        for (int it = 0; it < 2; ++it) {
            int idx = tid + it * 256;
            int e = idx >> 3, r = idx & 7;
            const float* s = ea + (size_t)s_perm[e] * DE + r * 8;
            float4 u = *(const float4*)s;
            float4 v = *(const float4*)(s + 4);
            ushort o[8];
            o[0] = f2bf(u.x); o[1] = f2bf(u.y); o[2] = f2bf(u.z); o[3] = f2bf(u.w);
            o[4] = f2bf(v.x); o[5] = f2bf(v.y); o[6] = f2bf(v.z); o[7] = f2bf(v.w);
            *(uint4*)(&zt[e][128 + r * 8]) = *(uint4*)o;
        }
    }
    __syncthreads();

    const int w = tid >> 6, l = tid & 63;
    const int col = l & 31;
    const int hi = l >> 5;
    f32x16 acc0[2], acc1[2];                 // [edge-tile][gate/softplus]
#pragma unroll
    for (int i = 0; i < 16; ++i) {
        acc0[0][i] = 0.f; acc1[0][i] = 0.f; acc0[1][i] = 0.f; acc1[1][i] = 0.f;
    }

    // K-global = 128 + kk*16 + hi*8 -> chunk = 16 + kk*2 + hi
    const ushort* wb0 = Wc + ((size_t)(16 + hi) * 256 + w * 64 + col) * 8;
    const ushort* wb1 = wb0 + 32 * 8;
#pragma unroll
    for (int kk = 0; kk < 12; ++kk) {        // K = 192
        const int k0 = kk * 16 + hi * 8;
        bf16x8 a0 = *(const bf16x8*)(&zt[col][k0]);
        bf16x8 a1 = *(const bf16x8*)(&zt[32 + col][k0]);
        bf16x8 b0 = *(const bf16x8*)(wb0 + (size_t)kk * 2 * 256 * 8);
        bf16x8 b1 = *(const bf16x8*)(wb1 + (size_t)kk * 2 * 256 * 8);
        acc0[0] = __builtin_amdgcn_mfma_f32_32x32x16_bf16(a0, b0, acc0[0], 0, 0, 0);
        acc1[0] = __builtin_amdgcn_mfma_f32_32x32x16_bf16(a0, b1, acc1[0], 0, 0, 0);
        acc0[1] = __builtin_amdgcn_mfma_f32_32x32x16_bf16(a1, b0, acc0[1], 0, 0, 0);
        acc1[1] = __builtin_amdgcn_mfma_f32_32x32x16_bf16(a1, b1, acc1[1], 0, 0, 0);
    }

    // epilogue: lane owns 32 edges x 1 channel (2 tiles); run-merge over sorted dsts.
    const float L2E = 1.44269504f, LN2 = 0.69314718f;
    const int ch = w * 32 + col;
    const int r0 = w * 64 + col;
    float run = 0.f;
    int prevd = s_dst[4 * hi];
    float bg = base[(size_t)prevd * 256 + r0];
    float bsv = base[(size_t)prevd * 256 + r0 + 32];
#pragma unroll
    for (int t = 0; t < 2; ++t) {
#pragma unroll
        for (int grp = 0; grp < 4; ++grp) {
            const int4 d4 = *(const int4*)(&s_dst[t * 32 + grp * 8 + 4 * hi]);
#pragma unroll
            for (int j = 0; j < 4; ++j) {
                const int q = grp * 4 + j;
                const int d = (j == 0) ? d4.x : (j == 1) ? d4.y : (j == 2) ? d4.z : d4.w;
                if (d != prevd) {
                    unsafeAtomicAdd(xnew + (size_t)prevd * C + ch, run);
                    run = 0.f;
                    prevd = d;
                    bg = base[(size_t)d * 256 + r0];
                    bsv = base[(size_t)d * 256 + r0 + 32];
                }
                float g = (t ? acc0[1][q] : acc0[0][q]) + bg;
                float s = (t ? acc1[1][q] : acc1[0][q]) + bsv;
                float gate = __builtin_amdgcn_rcpf(1.0f + __builtin_amdgcn_exp2f(-L2E * g));
                float sp = fmaf(LN2,
                                __builtin_amdgcn_logf(1.0f + __builtin_amdgcn_exp2f(-L2E * fabsf(s))),
                                fmaxf(s, 0.0f));
                run = fmaf(gate, sp, run);
            }
        }
    }
    unsafeAtomicAdd(xnew + (size_t)prevd * C + ch, run);
}

// ---------------- MLP GEMM1 (MFMA): fp32 in, h16 = bf16(x @ W1^T + b1), col stats ----------------
__global__ __launch_bounds__(256) void k_mlp1_mfma(
    const float* __restrict__ x, const ushort* __restrict__ W1T,
    const float* __restrict__ b1, ushort* __restrict__ h16,
    float* __restrict__ colsum, float* __restrict__ colsq)
{
    __shared__ ushort xs[64][136];
    const int tid = threadIdx.x;
    const int n0 = blockIdx.x * 64;
    const int ch0 = blockIdx.y * 128;
#pragma unroll
    for (int it = 0; it < 4; ++it) {
        int idx = tid + it * 256;       // 1024 chunks
        int e = idx >> 4, c = (idx & 15) * 8;
        int rr = n0 + e; if (rr >= NN) rr = NN - 1;
        const float* s = x + (size_t)rr * C + c;
        float4 u = *(const float4*)s;
        float4 v = *(const float4*)(s + 4);
        ushort o[8];
        o[0] = f2bf(u.x); o[1] = f2bf(u.y); o[2] = f2bf(u.z); o[3] = f2bf(u.w);
        o[4] = f2bf(v.x); o[5] = f2bf(v.y); o[6] = f2bf(v.z); o[7] = f2bf(v.w);
        *(uint4*)(&xs[e][c]) = *(uint4*)o;
    }
    __syncthreads();
    const int w = tid >> 6, l = tid & 63, lr = l & 15, lq = l >> 4, kp = lq * 8;
    const int cb = ch0 + w * 32;
    f32x4 acc[4][2];
#pragma unroll
    for (int rt = 0; rt < 4; ++rt) { acc[rt][0] = (f32x4){0,0,0,0}; acc[rt][1] = (f32x4){0,0,0,0}; }
    for (int kk = 0; kk < 4; ++kk) {
        int k0 = kk * 32 + kp;
        bf16x8 a[4], b[2];
#pragma unroll
        for (int rt = 0; rt < 4; ++rt) a[rt] = *(const bf16x8*)(&xs[rt * 16 + lr][k0]);
#pragma unroll
        for (int j = 0; j < 2; ++j)
            b[j] = *(const bf16x8*)(W1T + (((size_t)(kk * 4 + lq) * HD + cb + j * 16 + lr) << 3));
#pragma unroll
        for (int rt = 0; rt < 4; ++rt)
#pragma unroll
            for (int j = 0; j < 2; ++j)
                acc[rt][j] = __builtin_amdgcn_mfma_f32_16x16x32_bf16(a[rt], b[j], acc[rt][j], 0, 0, 0);
    }
    const int ro = lq * 4;
    float ps[2] = {0.f, 0.f}, pq[2] = {0.f, 0.f};
#pragma unroll
    for (int j = 0; j < 2; ++j) {
        const int ch = cb + j * 16 + lr;
        const float bv = b1[ch];
#pragma unroll
        for (int rt = 0; rt < 4; ++rt) {
#pragma unroll
            for (int q = 0; q < 4; ++q) {
                int row = n0 + rt * 16 + ro + q;
                float hv = acc[rt][j][q] + bv;
                if (row < NN) {
                    h16[(size_t)row * HD + ch] = f2bf(hv);
                    ps[j] += hv; pq[j] += hv * hv;
                }
            }
        }
    }
#pragma unroll
    for (int j = 0; j < 2; ++j) {
        ps[j] += __shfl_xor(ps[j], 16); ps[j] += __shfl_xor(ps[j], 32);
        pq[j] += __shfl_xor(pq[j], 16); pq[j] += __shfl_xor(pq[j], 32);
    }
    if (l < 16) {
#pragma unroll
        for (int j = 0; j < 2; ++j) {
            unsafeAtomicAdd(colsum + cb + j * 16 + lr, ps[j]);
            unsafeAtomicAdd(colsq + cb + j * 16 + lr, pq[j]);
        }
    }
}

// finalizes BN affine and re-zeros colsum/colsq for the next layer
__global__ void k_bnstats(float* __restrict__ colsum, float* __restrict__ colsq,
                          const float* __restrict__ g1, const float* __restrict__ be1,
                          float* __restrict__ bn_a, float* __restrict__ bn_b) {
    int c = threadIdx.x;   // 512
    float m = colsum[c] * (1.0f / NN);
    float v = colsq[c] * (1.0f / NN) - m * m;
    float istd = rsqrtf(fmaxf(v, 0.f) + EPSV);
    float a = g1[c] * istd;
    bn_a[c] = a;
    bn_b[c] = fmaf(-m, a, be1[c]);
    colsum[c] = 0.f;
    colsq[c] = 0.f;
}

// ---------------- MLP GEMM2 (MFMA) + fused LN stats ----------------
// x = xres + relu(a*h+b) @ W2^T + b2; per-graph sum/sumsq computed in-epilogue
// (each block owns 64 complete rows: 16 lr-lanes x 2 j x 4 waves = 128 channels).
__global__ __launch_bounds__(256) void k_mlp2_mfma(
    const ushort* __restrict__ h16, const float* __restrict__ bn_a, const float* __restrict__ bn_b,
    const ushort* __restrict__ W2T, const float* __restrict__ b2,
    const float* __restrict__ xres, float* __restrict__ xout,
    const int* __restrict__ nb_arr, float* __restrict__ gsum, float* __restrict__ gsq)
{
    __shared__ ushort hs[64][136];
    __shared__ float sh_rs[64], sh_rq[64];
    __shared__ int sh_g[64];
    const int tid = threadIdx.x;
    const int n0 = blockIdx.x * 64;
    const int nvalid = min(64, NN - n0);
    if (tid < 64) {
        sh_rs[tid] = 0.f; sh_rq[tid] = 0.f;
        int rr = n0 + tid;
        sh_g[tid] = nb_arr[(rr < NN) ? rr : (NN - 1)];
    }
    const int w = tid >> 6, l = tid & 63, lr = l & 15, lq = l >> 4, kp = lq * 8;
    f32x4 acc[4][2];
#pragma unroll
    for (int rt = 0; rt < 4; ++rt) { acc[rt][0] = (f32x4){0,0,0,0}; acc[rt][1] = (f32x4){0,0,0,0}; }

    for (int kc = 0; kc < 4; ++kc) {
#pragma unroll
        for (int it = 0; it < 4; ++it) {
            int idx = tid + it * 256;
            int e = idx >> 4, c = (idx & 15) * 8;
            int rr = n0 + e; if (rr >= NN) rr = NN - 1;
            int k = kc * 128 + c;
            bf16x8 hv = *(const bf16x8*)(h16 + (size_t)rr * HD + k);
            ushort o[8];
#pragma unroll
            for (int m = 0; m < 8; ++m) {
                float f = bf2f((ushort)hv[m]);
                f = fmaf(bn_a[k + m], f, bn_b[k + m]);
                o[m] = f2bf(fmaxf(f, 0.f));
            }
            *(uint4*)(&hs[e][c]) = *(uint4*)o;
        }
        __syncthreads();
        for (int kk = 0; kk < 4; ++kk) {
            int k0 = kk * 32 + kp;
            bf16x8 a[4], b[2];
#pragma unroll
            for (int rt = 0; rt < 4; ++rt) a[rt] = *(const bf16x8*)(&hs[rt * 16 + lr][k0]);
#pragma unroll
            for (int j = 0; j < 2; ++j)
                b[j] = *(const bf16x8*)(W2T + (((size_t)(kc * 16 + kk * 4 + lq) * C + w * 32 + j * 16 + lr) << 3));
#pragma unroll
            for (int rt = 0; rt < 4; ++rt)
#pragma unroll
                for (int j = 0; j < 2; ++j)
                    acc[rt][j] = __builtin_amdgcn_mfma_f32_16x16x32_bf16(a[rt], b[j], acc[rt][j], 0, 0, 0);
        }
        __syncthreads();
    }
    const int ro = lq * 4;
    const int chA = w * 32 + lr, chB = w * 32 + 16 + lr;
    const float bvA = b2[chA], bvB = b2[chB];
#pragma unroll
    for (int rt = 0; rt < 4; ++rt) {
#pragma unroll
        for (int q = 0; q < 4; ++q) {
            const int row = n0 + rt * 16 + ro + q;
            float s = 0.f, qq = 0.f;
            if (row < NN) {
                float v0 = xres[(size_t)row * C + chA] + acc[rt][0][q] + bvA;
                float v1 = xres[(size_t)row * C + chB] + acc[rt][1][q] + bvB;
                xout[(size_t)row * C + chA] = v0;
                xout[(size_t)row * C + chB] = v1;
                s = v0 + v1;
                qq = v0 * v0 + v1 * v1;
            }
            // reduce across the 16 lr-lanes (bits 0..3 of lane id)
            s += __shfl_xor(s, 1); qq += __shfl_xor(qq, 1);
            s += __shfl_xor(s, 2); qq += __shfl_xor(qq, 2);
            s += __shfl_xor(s, 4); qq += __shfl_xor(qq, 4);
            s += __shfl_xor(s, 8); qq += __shfl_xor(qq, 8);
            if (lr == 0 && row < NN) {
                const int rl = rt * 16 + ro + q;
                atomicAdd(&sh_rs[rl], s);       // LDS atomic: combine 4 waves
                atomicAdd(&sh_rq[rl], qq);
            }
        }
    }
    __syncthreads();
    if (tid == 0) {
        int pg = sh_g[0];
        float rs = 0.f, rq = 0.f;
        for (int i = 0; i < nvalid; ++i) {
            int g = sh_g[i];
            if (g != pg) {
                unsafeAtomicAdd(&gsum[pg], rs);
                unsafeAtomicAdd(&gsq[pg], rq);
                rs = 0.f; rq = 0.f; pg = g;
            }
            rs += sh_rs[i]; rq += sh_rq[i];
        }
        unsafeAtomicAdd(&gsum[pg], rs);
        unsafeAtomicAdd(&gsq[pg], rq);
    }
}

// finalizes LN mean/istd and re-zeros gsum/gsq for the next layer
__global__ void k_lnfin(float* __restrict__ gsum, float* __restrict__ gsq,
                        const int* __restrict__ gcount,
                        float* __restrict__ gmean, float* __restrict__ gistd) {
    int g = threadIdx.x;
    float cnt = fmaxf((float)gcount[g], 1.0f) * (float)C;
    float m = gsum[g] / cnt;
    float v = gsq[g] / cnt - m * m;
    gmean[g] = m;
    gistd[g] = rsqrtf(fmaxf(v, 0.f) + EPSV);
    gsum[g] = 0.f;
    gsq[g] = 0.f;
}

// fused: fp32 out (+ optional bf16 copy for next edge layer + fp32 residual copy)
__global__ __launch_bounds__(256) void k_lnapply(
    const float* __restrict__ x2, const int* __restrict__ nb_arr,
    const float* __restrict__ gmean, const float* __restrict__ gistd,
    const float* __restrict__ lnw, const float* __restrict__ lnb,
    float* __restrict__ out, ushort* __restrict__ bfout, float* __restrict__ xbout, int aux)
{
    int idx = blockIdx.x * 256 + threadIdx.x;   // NC/4 threads
    int elem = idx * 4;
    int n = elem >> 7, c = elem & 127;
    int g = nb_arr[n];
    float m = gmean[g], is = gistd[g];
    float4 v = *(const float4*)(x2 + elem);
    float4 wv = *(const float4*)(lnw + c);
    float4 bv = *(const float4*)(lnb + c);
    float4 r;
    r.x = (v.x - m) * is * wv.x + bv.x;
    r.y = (v.y - m) * is * wv.y + bv.y;
    r.z = (v.z - m) * is * wv.z + bv.z;
    r.w = (v.w - m) * is * wv.w + bv.w;
    *(float4*)(out + elem) = r;
    if (aux) {
        ushort4 o;
        o.x = f2bf(r.x); o.y = f2bf(r.y); o.z = f2bf(r.z); o.w = f2bf(r.w);
        *(ushort4*)(bfout + elem) = o;
        *(float4*)(xbout + elem) = r;
    }
}

// ---------------- launcher ----------------
extern "C" void kernel_launch(void* const* d_in, const int* in_sizes, int n_in,
                              void* d_out, int out_size, void* d_ws, size_t ws_size,
                              hipStream_t stream) {
    const float* x_in = (const float*)d_in[0];
    const int* node_batch = (const int*)d_in[1];
    const int* ei = (const int*)d_in[2];
    const float* ea = (const float*)d_in[3];
    const float* Wf = (const float*)d_in[4];
    const float* bfv = (const float*)d_in[5];
    const float* Ws = (const float*)d_in[6];
    const float* bsv = (const float*)d_in[7];
    const float* W1 = (const float*)d_in[8];
    const float* b1 = (const float*)d_in[9];
    const float* g1 = (const float*)d_in[10];
    const float* be1 = (const float*)d_in[11];
    const float* W2 = (const float*)d_in[12];
    const float* b2 = (const float*)d_in[13];
    const float* lnw = (const float*)d_in[14];
    const float* lnb = (const float*)d_in[15];
    float* out = (float*)d_out;

    const size_t NC = (size_t)NN * C;       // 2,560,000
    const size_t NH = (size_t)NN * HD;      // 10,240,000
    float* p = (float*)d_ws;
    float* xa = p; p += NC;
    float* xb = p; p += NC;
    ushort* h16 = (ushort*)p; p += NH / 2;  // base[N][256] fp32 aliases this (exactly NH/2 floats)
    float* base = (float*)h16;
    ushort* bfx = (ushort*)p; p += NC / 2;
    ushort* Wce = (ushort*)p; p += 40960;          // 81920 ushorts
    ushort* W116 = (ushort*)p; p += 98304;         // 3*65536 ushorts (k-major)
    ushort* W216 = (ushort*)p; p += 98304;
    float* bc = p; p += 256;
    float* bn_a = p; p += 512;
    float* bn_b = p; p += 512;
    float* colsum = p; p += 512;
    float* colsq = p; p += 512;                    // contiguous with colsum
    float* gsum = p; p += 32;
    float* gsq = p; p += 32;                       // contiguous with gsum
    float* gmean = p; p += 32;
    float* gistd = p; p += 32;
    int* gcount = (int*)p; p += 32;
    int* deg = (int*)p; p += NN;
    int* cursor = (int*)p; p += NN;
    int* bsum = (int*)p; p += 128;
    int* boff = (int*)p; p += 128;
    int* perm = (int*)p; p += NE;
    ushort* ea16p = (ushort*)p; p += (size_t)NE * DE / 2;   // 40.96M ushorts

    const bool sea = ws_size >= (size_t)((char*)p - (char*)d_ws);
    const int NB_SCAN = (NN + 255) / 256;          // 79

    // ---- one-time per call: sort edges by dst, graph counts, weight preps ----
    hipMemsetAsync(deg, 0, NN * 4, stream);
    k_hist<<<NE / 256, 256, 0, stream>>>(ei, deg);
    k_scan1<<<NB_SCAN, 256, 0, stream>>>(deg, cursor, bsum);
    k_scan2<<<1, 1, 0, stream>>>(bsum, boff, NB_SCAN);
    k_scan3<<<NB_SCAN, 256, 0, stream>>>(cursor, boff);
    k_scatter<<<NE / 256, 256, 0, stream>>>(ei, cursor, perm);
    if (sea) k_permea<<<NE / 64, 256, 0, stream>>>(ea, perm, ea16p);

    hipMemsetAsync(gcount, 0, G * 4, stream);
    k_gcount<<<(NN + 255) / 256, 256, 0, stream>>>(node_batch, gcount);

    k_prepw1T<<<768, 256, 0, stream>>>(W1, W116);
    k_prepw2T<<<768, 256, 0, stream>>>(W2, W216);

    // stats accumulators zeroed once; producers re-zero them each layer
    hipMemsetAsync(colsum, 0, 1024 * 4, stream);
    hipMemsetAsync(gsum, 0, 64 * 4, stream);

    hipMemcpyAsync(xa, x_in, NC * 4, hipMemcpyDeviceToDevice, stream);
    hipMemcpyAsync(xb, x_in, NC * 4, hipMemcpyDeviceToDevice, stream);
    k_cast_x<<<NC / 1024, 256, 0, stream>>>(x_in, bfx);

    for (int l = 0; l < LL; ++l) {
        k_prepw32T<<<320, 256, 0, stream>>>(
            Wf + (size_t)l * C * ZD, bfv + (size_t)l * C,
            Ws + (size_t)l * C * ZD, bsv + (size_t)l * C, Wce, bc);
        k_base<<<NN / 32, 256, 0, stream>>>(bfx, Wce, bc, base);
        // xb already holds x (residual); edge accumulates messages into it
        if (sea)
            k_edge64<true><<<NE / 64, 256, 0, stream>>>(bfx, ei, perm, ea, ea16p, Wce, base, xb);
        else
            k_edge64<false><<<NE / 64, 256, 0, stream>>>(bfx, ei, perm, ea, ea16p, Wce, base, xb);

        k_mlp1_mfma<<<dim3(313, 4), 256, 0, stream>>>(xb,
            W116 + (size_t)l * 65536, b1 + (size_t)l * HD, h16, colsum, colsq);
        k_bnstats<<<1, HD, 0, stream>>>(colsum, colsq,
            g1 + (size_t)l * HD, be1 + (size_t)l * HD, bn_a, bn_b);

        k_mlp2_mfma<<<313, 256, 0, stream>>>(h16, bn_a, bn_b,
            W216 + (size_t)l * 65536, b2 + (size_t)l * C, xb, xa,
            node_batch, gsum, gsq);

        k_lnfin<<<1, G, 0, stream>>>(gsum, gsq, gcount, gmean, gistd);
        float* dstp = (l == LL - 1) ? out : xa;
        k_lnapply<<<NC / 1024, 256, 0, stream>>>(xa, node_batch, gmean, gistd,
            lnw + (size_t)l * C, lnb + (size_t)l * C, dstp, bfx, xb, (l != LL - 1) ? 1 : 0);
    }
}